// Round 5
// baseline (3867.530 us; speedup 1.0000x reference)
//
#include <hip/hip_runtime.h>
#include <hip/hip_bf16.h>
#include <math.h>

#define N_NODES 100000
#define DIM 64
#define E_EDGES 1600000
#define N_ADJ 4
#define NB 1563              // ceil(100000/64) buckets of 64 rows
#define NBTOT (N_ADJ * NB)   // 6252
#define P1_BLK 1024
#define P1_CHUNK 12800
#define P1_GRIDX 125         // 125 * 12800 = 1.6M
#define NVOFF ((u32)N_NODES * DIM)   // u16 elements between s0 and s1
#define ASTR 65              // padded LDS accum stride (bank spread)

typedef unsigned short u16;
typedef unsigned int u32;

// ---- used-adjacency mask from device-side idxes ----
__global__ void mask_kernel(const int* __restrict__ iseq,
                            const int* __restrict__ ires,
                            int* __restrict__ used) {
    if (threadIdx.x == 0) {
        used[0] = used[1] = used[2] = used[3] = 0;
        used[iseq[0]] = 1; used[iseq[1]] = 1;
        used[iseq[2]] = 1; used[iseq[3]] = 1;
        used[ires[0]] = 1; used[ires[1]] = 1;
    }
}

// ---------------- GEMM: s0 = bf16(x @ W + b) ----------------
__global__ __launch_bounds__(256) void gemm_kernel(
    const float* __restrict__ x, const float* __restrict__ W,
    const float* __restrict__ b, u16* __restrict__ h) {
    __shared__ float Ws[DIM * DIM];
    __shared__ float xs[16 * DIM];
    const int tid = threadIdx.x;
    const long row0 = (long)blockIdx.x * 16;
    for (int i = tid; i < DIM * DIM; i += 256) Ws[i] = W[i];
    for (int i = tid; i < 16 * DIM; i += 256) xs[i] = x[row0 * DIM + i];
    __syncthreads();
    const int lane = tid & 63;
    const int grp  = tid >> 6;
    const float bias = b[lane];
    #pragma unroll
    for (int rr = 0; rr < 4; ++rr) {
        const int r = grp * 4 + rr;
        float acc = bias;
        #pragma unroll
        for (int k = 0; k < DIM; ++k)
            acc += xs[r * DIM + k] * Ws[k * DIM + lane];
        __hip_bfloat16 hb = __float2bfloat16(acc);
        h[(row0 + r) * DIM + lane] = *(u16*)&hb;
    }
}

// ---- hist: LDS-aggregated bucket counts -> gcnt ----
__global__ __launch_bounds__(1024) void hist_kernel(
    const int* __restrict__ rows, int* __restrict__ gcnt,
    const int* __restrict__ used) {
    __shared__ int h[NB];
    const int a = blockIdx.y;
    if (!used[a]) return;
    const int tid = threadIdx.x;
    const long e0 = (long)a * E_EDGES + (long)blockIdx.x * P1_CHUNK;
    for (int i = tid; i < NB; i += P1_BLK) h[i] = 0;
    __syncthreads();
    for (int i = tid; i < P1_CHUNK; i += P1_BLK)
        atomicAdd(&h[rows[e0 + i] >> 6], 1);
    __syncthreads();
    for (int bk = tid; bk < NB; bk += P1_BLK) {
        const int c = h[bk];
        if (c) atomicAdd(&gcnt[a * NB + bk], c);
    }
}

// ---- scan: exact exclusive scan of 6252 bucket counts (1 block) ----
__global__ __launch_bounds__(1024) void scan_kernel(
    const int* __restrict__ gcnt, int* __restrict__ bbase,
    int* __restrict__ cursor) {
    __shared__ int wsum[16];
    const int tid = threadIdx.x, lane = tid & 63, wave = tid >> 6;
    int pre[7];
    int tsum = 0;
    #pragma unroll
    for (int k = 0; k < 7; ++k) {
        const int idx = tid * 7 + k;
        const int v = (idx < NBTOT) ? gcnt[idx] : 0;
        pre[k] = tsum;
        tsum += v;
    }
    int incl = tsum;
    #pragma unroll
    for (int o = 1; o < 64; o <<= 1) {
        const int t = __shfl_up(incl, o);
        if (lane >= o) incl += t;
    }
    if (lane == 63) wsum[wave] = incl;
    __syncthreads();
    if (tid == 0) {
        int run = 0;
        #pragma unroll
        for (int w = 0; w < 16; ++w) { const int t = wsum[w]; wsum[w] = run; run += t; }
    }
    __syncthreads();
    const int texcl = incl - tsum + wsum[wave];
    #pragma unroll
    for (int k = 0; k < 7; ++k) {
        const int idx = tid * 7 + k;
        if (idx < NBTOT) {
            const int v = texcl + pre[k];
            bbase[idx]  = v;
            cursor[idx] = v;
        }
    }
    if (tid == 0) bbase[NBTOT] = N_ADJ * E_EDGES;
}

// ---- place: reserve per-(block,bucket) runs, pack edges (unsorted in bucket) ----
__global__ __launch_bounds__(1024) void place_kernel(
    const int* __restrict__ rows, const int* __restrict__ cols,
    const float* __restrict__ vals, int* __restrict__ cursor,
    int2* __restrict__ bins, const int* __restrict__ used) {
    __shared__ int h[NB];
    const int a = blockIdx.y;
    if (!used[a]) return;
    const int tid = threadIdx.x;
    const long e0 = (long)a * E_EDGES + (long)blockIdx.x * P1_CHUNK;
    for (int i = tid; i < NB; i += P1_BLK) h[i] = 0;
    __syncthreads();
    for (int i = tid; i < P1_CHUNK; i += P1_BLK)
        atomicAdd(&h[rows[e0 + i] >> 6], 1);
    __syncthreads();
    for (int bk = tid; bk < NB; bk += P1_BLK) {
        const int c = h[bk];
        if (c) h[bk] = atomicAdd(&cursor[a * NB + bk], c);  // abs base of run
    }
    __syncthreads();
    for (int i = tid; i < P1_CHUNK; i += P1_BLK) {
        const int r  = rows[e0 + i];
        const int bk = r >> 6;
        const int slot = atomicAdd(&h[bk], 1);              // absolute bins index
        bins[slot] = make_int2((cols[e0 + i] << 6) | (r & 63),
                               __float_as_int(vals[e0 + i]));
    }
}

// ---------------- Bucket SpMM core ----------------
// One block = one 64-row bucket. Streams the bucket's UNSORTED bins run
// (coalesced 8B-per-lane record loads), gathers each edge's 128 B source
// row (8 lanes x dwordx4), and atomicAdds v*src into a padded LDS fp32
// accumulator acc[64][65]. Zero-padded records (t>=n) gather row 0 of the
// segment base times v=0: harmless. stg is per-wave private (no barrier).
#define SPMM_BATCH(SEGBASE)                                                   \
    for (int e0 = (wave << 6); e0 < n; e0 += 256) {                           \
        const int t = e0 + lane;                                              \
        u32 rx = 0u, ry = 0u;                                                 \
        if (t < n) {                                                          \
            const long long raw = __builtin_nontemporal_load(                 \
                (const long long*)(bins + p0 + t));                           \
            rx = (u32)(int)raw;                                               \
            ry = (u32)(int)(raw >> 32);                                       \
        }                                                                     \
        stg[tid] = make_uint2(rx, ry);                                        \
        const int nrem = n - e0;                                              \
        const bool hi = (nrem > 32);                                          \
        u32 x0, x1, x2, x3; int r0, r1, r2, r3;                               \
        float v0, v1, v2, v3;                                                 \
        uint4 w0, w1, w2, w3;                                                 \
        {                                                                     \
            const uint2 a0 = stg[(wave << 6) + grp];                          \
            const uint2 a1 = stg[(wave << 6) + 8 + grp];                      \
            const uint2 a2 = stg[(wave << 6) + 16 + grp];                     \
            const uint2 a3 = stg[(wave << 6) + 24 + grp];                     \
            x0 = a0.x & 0xFFFFFFC0u; r0 = (int)(a0.x & 63u);                  \
            v0 = __int_as_float((int)a0.y);                                   \
            x1 = a1.x & 0xFFFFFFC0u; r1 = (int)(a1.x & 63u);                  \
            v1 = __int_as_float((int)a1.y);                                   \
            x2 = a2.x & 0xFFFFFFC0u; r2 = (int)(a2.x & 63u);                  \
            v2 = __int_as_float((int)a2.y);                                   \
            x3 = a3.x & 0xFFFFFFC0u; r3 = (int)(a3.x & 63u);                  \
            v3 = __int_as_float((int)a3.y);                                   \
            w0 = *(const uint4*)((SEGBASE) + x0);                             \
            w1 = *(const uint4*)((SEGBASE) + x1);                             \
            w2 = *(const uint4*)((SEGBASE) + x2);                             \
            w3 = *(const uint4*)((SEGBASE) + x3);                             \
        }                                                                     \
        u32 x4, x5, x6, x7; int r4, r5, r6, r7;                               \
        float v4, v5, v6, v7;                                                 \
        uint4 w4, w5, w6, w7;                                                 \
        if (hi) {                                                             \
            const uint2 a4 = stg[(wave << 6) + 32 + grp];                     \
            const uint2 a5 = stg[(wave << 6) + 40 + grp];                     \
            const uint2 a6 = stg[(wave << 6) + 48 + grp];                     \
            const uint2 a7 = stg[(wave << 6) + 56 + grp];                     \
            x4 = a4.x & 0xFFFFFFC0u; r4 = (int)(a4.x & 63u);                  \
            v4 = __int_as_float((int)a4.y);                                   \
            x5 = a5.x & 0xFFFFFFC0u; r5 = (int)(a5.x & 63u);                  \
            v5 = __int_as_float((int)a5.y);                                   \
            x6 = a6.x & 0xFFFFFFC0u; r6 = (int)(a6.x & 63u);                  \
            v6 = __int_as_float((int)a6.y);                                   \
            x7 = a7.x & 0xFFFFFFC0u; r7 = (int)(a7.x & 63u);                  \
            v7 = __int_as_float((int)a7.y);                                   \
            w4 = *(const uint4*)((SEGBASE) + x4);                             \
            w5 = *(const uint4*)((SEGBASE) + x5);                             \
            w6 = *(const uint4*)((SEGBASE) + x6);                             \
            w7 = *(const uint4*)((SEGBASE) + x7);                             \
        }                                                                     \
        ACC8(w0, v0, r0) ACC8(w1, v1, r1) ACC8(w2, v2, r2) ACC8(w3, v3, r3)   \
        if (hi) {                                                             \
            ACC8(w4, v4, r4) ACC8(w5, v5, r5)                                 \
            ACC8(w6, v6, r6) ACC8(w7, v7, r7)                                 \
        }                                                                     \
    }

#define ACC8(W, V, R) {                                                       \
    float* ap = accbase + (R) * ASTR;                                         \
    atomicAdd(ap + 0, (V) * __int_as_float((W).x << 16));                     \
    atomicAdd(ap + 1, (V) * __int_as_float((W).x & 0xffff0000u));             \
    atomicAdd(ap + 2, (V) * __int_as_float((W).y << 16));                     \
    atomicAdd(ap + 3, (V) * __int_as_float((W).y & 0xffff0000u));             \
    atomicAdd(ap + 4, (V) * __int_as_float((W).z << 16));                     \
    atomicAdd(ap + 5, (V) * __int_as_float((W).z & 0xffff0000u));             \
    atomicAdd(ap + 6, (V) * __int_as_float((W).w << 16));                     \
    atomicAdd(ap + 7, (V) * __int_as_float((W).w & 0xffff0000u)); }

// s1 = bf16(0.5*(A[i0]+A[i1]) @ s0), bucket-granularity
__global__ __launch_bounds__(256) void spmm_s1_kernel(
    const u16* __restrict__ s0, u16* __restrict__ s1v,
    const int2* __restrict__ bins, const int* __restrict__ gcnt,
    const int* __restrict__ bbase, const int* __restrict__ idx) {
    __shared__ float acc[64 * ASTR];
    __shared__ uint2 stg[256];
    const int tid = threadIdx.x;
    const int bk  = blockIdx.x;
    for (int i = tid; i < 64 * ASTR; i += 256) acc[i] = 0.f;
    __syncthreads();
    const int lane = tid & 63, wave = tid >> 6;
    const int grp  = lane >> 3, sub = lane & 7;
    const int dsub = sub << 3;
    const u16* mybase = s0 + dsub;
    float* accbase = acc + dsub;

    #pragma unroll
    for (int seg = 0; seg < 2; ++seg) {
        const int key = idx[seg] * NB + bk;
        const int p0  = bbase[key];
        const int n   = gcnt[key];
        SPMM_BATCH(mybase)
    }
    __syncthreads();
    const int row_l = tid >> 2, qq = tid & 3;
    const int row_g = (bk << 6) + row_l;
    if (row_g < N_NODES) {
        const float* ap = acc + row_l * ASTR + (qq << 4);
        u32 p[8];
        #pragma unroll
        for (int q = 0; q < 8; ++q) {
            __hip_bfloat16 blo = __float2bfloat16(0.5f * ap[2 * q]);
            __hip_bfloat16 bhi = __float2bfloat16(0.5f * ap[2 * q + 1]);
            p[q] = (u32)(*(u16*)&blo) | ((u32)(*(u16*)&bhi) << 16);
        }
        uint4* po = (uint4*)(s1v + (long)row_g * DIM + (qq << 4));
        po[0] = make_uint4(p[0], p[1], p[2], p[3]);
        po[1] = make_uint4(p[4], p[5], p[6], p[7]);
    }
}

// out = gelu(LN(0.5*(seq@s1) + 0.5*(res@s0))), bucket-granularity
__global__ __launch_bounds__(256) void spmm_out_ln_gelu_kernel(
    const u16* __restrict__ s0, float* __restrict__ out,
    const int2* __restrict__ bins, const int* __restrict__ gcnt,
    const int* __restrict__ bbase, const int* __restrict__ idx_seq1,
    const int* __restrict__ idx_res, const float* __restrict__ gamma,
    const float* __restrict__ beta) {
    __shared__ float acc[64 * ASTR];
    __shared__ uint2 stg[256];
    const int tid = threadIdx.x;
    const int bk  = blockIdx.x;
    for (int i = tid; i < 64 * ASTR; i += 256) acc[i] = 0.f;
    __syncthreads();
    const int lane = tid & 63, wave = tid >> 6;
    const int grp  = lane >> 3, sub = lane & 7;
    const int dsub = sub << 3;
    const u16* mybase = s0 + dsub;
    float* accbase = acc + dsub;

    #pragma unroll
    for (int seg = 0; seg < 4; ++seg) {
        const int a   = (seg < 2) ? idx_seq1[seg] : idx_res[seg - 2];
        const int key = a * NB + bk;
        const int p0  = bbase[key];
        const int n   = gcnt[key];
        const u16* segbase = (seg < 2) ? (mybase + NVOFF) : mybase;
        SPMM_BATCH(segbase)
    }
    __syncthreads();

    const int row_l = tid >> 2, qq = tid & 3;
    const int row_g = (bk << 6) + row_l;
    const float* ap = acc + row_l * ASTR + (qq << 4);
    float vals[16];
    float s = 0.f, s2 = 0.f;
    #pragma unroll
    for (int j = 0; j < 16; ++j) {
        const float xv = 0.5f * ap[j];
        vals[j] = xv;
        s += xv; s2 += xv * xv;
    }
    s  += __shfl_xor(s, 1);  s  += __shfl_xor(s, 2);
    s2 += __shfl_xor(s2, 1); s2 += __shfl_xor(s2, 2);
    const float mu  = s * (1.0f / DIM);
    const float var = s2 * (1.0f / DIM) - mu * mu;
    const float inv = rsqrtf(var + 1e-5f);
    if (row_g < N_NODES) {
        const float4* gp = (const float4*)(gamma + (qq << 4));
        const float4* bp = (const float4*)(beta  + (qq << 4));
        float* po = out + (long)row_g * DIM + (qq << 4);
        #pragma unroll
        for (int q = 0; q < 4; ++q) {
            const float4 gm = gp[q];
            const float4 bt = bp[q];
            float4 o;
            float y;
            y = (vals[4 * q + 0] - mu) * inv * gm.x + bt.x;
            o.x = 0.5f * y * (1.0f + erff(y * 0.70710678118654752f));
            y = (vals[4 * q + 1] - mu) * inv * gm.y + bt.y;
            o.y = 0.5f * y * (1.0f + erff(y * 0.70710678118654752f));
            y = (vals[4 * q + 2] - mu) * inv * gm.z + bt.z;
            o.z = 0.5f * y * (1.0f + erff(y * 0.70710678118654752f));
            y = (vals[4 * q + 3] - mu) * inv * gm.w + bt.w;
            o.w = 0.5f * y * (1.0f + erff(y * 0.70710678118654752f));
            ((float4*)po)[q] = o;
        }
    }
}

extern "C" void kernel_launch(void* const* d_in, const int* in_sizes, int n_in,
                              void* d_out, int out_size, void* d_ws, size_t ws_size,
                              hipStream_t stream) {
    const float* x     = (const float*)d_in[0];
    const float* W     = (const float*)d_in[1];
    const float* b     = (const float*)d_in[2];
    const int*   rows  = (const int*)d_in[3];
    const int*   cols  = (const int*)d_in[4];
    const float* vals  = (const float*)d_in[5];
    const float* gamma = (const float*)d_in[6];
    const float* beta  = (const float*)d_in[7];
    const int*   idxes_seq = (const int*)d_in[8];   // [2,2] flat
    const int*   idxes_res = (const int*)d_in[9];   // [1,2] flat
    float* out = (float*)d_out;

    // workspace layout: ~77 MB total
    int2*  bins    = (int2*)d_ws;                                // 4E int2 = 51.2 MB
    u16*   s0      = (u16*)(bins + (size_t)N_ADJ * E_EDGES);     // 12.8 MB bf16
    u16*   s1      = s0 + (size_t)N_NODES * DIM;                 // 12.8 MB bf16 (= s0 + NVOFF)
    int*   gcnt    = (int*)(s1 + (size_t)N_NODES * DIM);         // 6252 ints
    int*   bbase   = gcnt + NBTOT;                               // 6253 ints
    int*   cursor  = bbase + NBTOT + 1;                          // 6252 ints
    int*   used    = cursor + NBTOT;                             // 4 ints

    hipMemsetAsync(gcnt, 0, (size_t)NBTOT * sizeof(int), stream);

    mask_kernel<<<1, 64, 0, stream>>>(idxes_seq, idxes_res, used);
    gemm_kernel<<<N_NODES / 16, 256, 0, stream>>>(x, W, b, s0);

    dim3 egrid(P1_GRIDX, N_ADJ);
    hist_kernel <<<egrid, P1_BLK, 0, stream>>>(rows, gcnt, used);
    scan_kernel <<<1, P1_BLK, 0, stream>>>(gcnt, bbase, cursor);
    place_kernel<<<egrid, P1_BLK, 0, stream>>>(rows, cols, vals, cursor, bins, used);

    // s1 = 0.5*(A[i0]+A[i1]) @ s0   (bucket blocks, unsorted bins)
    spmm_s1_kernel<<<NB, 256, 0, stream>>>(s0, s1, bins, gcnt, bbase, idxes_seq);
    // out = gelu(LN(0.5*(A[i2]+A[i3])@s1 + 0.5*(A[r0]+A[r1])@s0))
    spmm_out_ln_gelu_kernel<<<NB, 256, 0, stream>>>(
        s0, out, bins, gcnt, bbase, idxes_seq + 2, idxes_res, gamma, beta);
}

// Round 6
// 718.802 us; speedup vs baseline: 5.3805x; 5.3805x over previous
//
#include <hip/hip_runtime.h>
#include <hip/hip_bf16.h>
#include <math.h>

#define N_NODES 100000
#define DIM 64
#define E_EDGES 1600000
#define N_ADJ 4
#define NROWTOT (N_ADJ * N_NODES)   // 400000 per-(adj,row) counters
#define P1_BLK 1024
#define P1_CHUNK 12800
#define P1_GRIDX 125         // 125 * 12800 = 1.6M
#define SCHUNK 1024
#define NCHUNKS 391          // ceil(400000/1024)
#define NVOFF ((u32)N_NODES * DIM)   // u16 elements between s0 and s1

typedef unsigned short u16;
typedef unsigned int u32;

// ---- used-adjacency mask from device-side idxes ----
__global__ void mask_kernel(const int* __restrict__ iseq,
                            const int* __restrict__ ires,
                            int* __restrict__ used) {
    if (threadIdx.x == 0) {
        used[0] = used[1] = used[2] = used[3] = 0;
        used[iseq[0]] = 1; used[iseq[1]] = 1;
        used[iseq[2]] = 1; used[iseq[3]] = 1;
        used[ires[0]] = 1; used[ires[1]] = 1;
    }
}

// ---------------- GEMM: s0 = bf16(x @ W + b) ----------------
__global__ __launch_bounds__(256) void gemm_kernel(
    const float* __restrict__ x, const float* __restrict__ W,
    const float* __restrict__ b, u16* __restrict__ h) {
    __shared__ float Ws[DIM * DIM];
    __shared__ float xs[16 * DIM];
    const int tid = threadIdx.x;
    const long row0 = (long)blockIdx.x * 16;
    for (int i = tid; i < DIM * DIM; i += 256) Ws[i] = W[i];
    for (int i = tid; i < 16 * DIM; i += 256) xs[i] = x[row0 * DIM + i];
    __syncthreads();
    const int lane = tid & 63;
    const int grp  = tid >> 6;
    const float bias = b[lane];
    #pragma unroll
    for (int rr = 0; rr < 4; ++rr) {
        const int r = grp * 4 + rr;
        float acc = bias;
        #pragma unroll
        for (int k = 0; k < DIM; ++k)
            acc += xs[r * DIM + k] * Ws[k * DIM + lane];
        __hip_bfloat16 hb = __float2bfloat16(acc);
        h[(row0 + r) * DIM + lane] = *(u16*)&hb;
    }
}

// ---- rowhist: per-(adj,row) counts via direct global atomics ----
__global__ __launch_bounds__(1024) void rowhist_kernel(
    const int* __restrict__ rows, int* __restrict__ gcnt,
    const int* __restrict__ used) {
    const int a = blockIdx.y;
    if (!used[a]) return;
    const int tid = threadIdx.x;
    const long e0 = (long)a * E_EDGES + (long)blockIdx.x * P1_CHUNK;
    const int abase = a * N_NODES;
    for (int i = tid; i < P1_CHUNK; i += P1_BLK)
        atomicAdd(&gcnt[abase + rows[e0 + i]], 1);
}

// ---- scanA: per-1024-chunk sums of gcnt -> psum[NCHUNKS] ----
__global__ __launch_bounds__(1024) void scanA_kernel(
    const int* __restrict__ gcnt, int* __restrict__ psum) {
    __shared__ int ws[16];
    const int tid = threadIdx.x;
    const int idx = blockIdx.x * SCHUNK + tid;
    int v = (idx < NROWTOT) ? gcnt[idx] : 0;
    #pragma unroll
    for (int o = 32; o > 0; o >>= 1) v += __shfl_xor(v, o);
    if ((tid & 63) == 0) ws[tid >> 6] = v;
    __syncthreads();
    if (tid == 0) {
        int s = 0;
        #pragma unroll
        for (int w = 0; w < 16; ++w) s += ws[w];
        psum[blockIdx.x] = s;
    }
}

// ---- scanB: exclusive scan of NCHUNKS partials (1 block, 512 thr) ----
__global__ __launch_bounds__(512) void scanB_kernel(int* __restrict__ psum) {
    __shared__ int ws[8];
    const int tid = threadIdx.x, lane = tid & 63, wave = tid >> 6;
    const int v = (tid < NCHUNKS) ? psum[tid] : 0;
    int incl = v;
    #pragma unroll
    for (int o = 1; o < 64; o <<= 1) {
        const int t = __shfl_up(incl, o);
        if (lane >= o) incl += t;
    }
    if (lane == 63) ws[wave] = incl;
    __syncthreads();
    if (tid == 0) {
        int run = 0;
        #pragma unroll
        for (int w = 0; w < 8; ++w) { const int t = ws[w]; ws[w] = run; run += t; }
    }
    __syncthreads();
    if (tid < NCHUNKS) psum[tid] = incl - v + ws[wave];
}

// ---- scanC: rowinfo[i] = (global exclusive base, count) ----
__global__ __launch_bounds__(1024) void scanC_kernel(
    const int* __restrict__ gcnt, const int* __restrict__ psum,
    int2* __restrict__ rowinfo) {
    __shared__ int ws[16];
    const int tid = threadIdx.x, lane = tid & 63, wave = tid >> 6;
    const int idx = blockIdx.x * SCHUNK + tid;
    const int v = (idx < NROWTOT) ? gcnt[idx] : 0;
    int incl = v;
    #pragma unroll
    for (int o = 1; o < 64; o <<= 1) {
        const int t = __shfl_up(incl, o);
        if (lane >= o) incl += t;
    }
    if (lane == 63) ws[wave] = incl;
    __syncthreads();
    if (tid == 0) {
        int run = 0;
        #pragma unroll
        for (int w = 0; w < 16; ++w) { const int t = ws[w]; ws[w] = run; run += t; }
    }
    __syncthreads();
    if (idx < NROWTOT) {
        const int excl = incl - v + ws[wave] + psum[blockIdx.x];
        // .x will be atomically bumped to (start+count) by place; consumer
        // recovers start = x - y.
        rowinfo[idx] = make_int2(excl, v);
    }
}

// ---- place_direct: each edge lands in its final row-sorted slot ----
__global__ __launch_bounds__(1024) void place_kernel(
    const int* __restrict__ rows, const int* __restrict__ cols,
    const float* __restrict__ vals, int* __restrict__ rowinfo_raw,
    int2* __restrict__ bins, const int* __restrict__ used) {
    const int a = blockIdx.y;
    if (!used[a]) return;
    const int tid = threadIdx.x;
    const long e0 = (long)a * E_EDGES + (long)blockIdx.x * P1_CHUNK;
    const int abase = a * N_NODES;
    for (int i = tid; i < P1_CHUNK; i += P1_BLK) {
        const int r = rows[e0 + i];
        const int slot = atomicAdd(&rowinfo_raw[(abase + r) << 1], 1);
        bins[slot] = make_int2(cols[e0 + i] << 6, __float_as_int(vals[e0 + i]));
    }
}

// ---------------- Pull gather core (round-2 structure) ----------------
// Wave = 1 row. 8 groups of 8 lanes; each edge's 64-dim bf16 row (128 B)
// loaded by 8 lanes as dwordx4. The 4 edge segments are virtually
// concatenated into t in [0, m); cascaded selects map t -> bins position
// and source offset. 4 slots deep per lane => 32 edges in flight.
__device__ __forceinline__ void gather4(
    const u16* __restrict__ base, const u32 nvoff,
    const int2* __restrict__ bins,
    const int2 i0, const int2 i1, const int2 i2, const int2 i3,
    const int grp, const int dsub, float acc[8])
{
    const int c1 = i0.y;
    const int c2 = c1 + i1.y;
    const int c3 = c2 + i2.y;
    const int m  = c3 + i3.y;
    const int b0 = i0.x;
    const int b1 = i1.x - c1;
    const int b2 = i2.x - c2;
    const int b3 = i3.x - c3;

    for (int T = grp; T < m; T += 32) {
        int x0, x1, x2, x3;
        float v0, v1, v2, v3;
        u32 so0, so1, so2, so3;
        #define SLOT(TT, XX, VV, SS) {                                        \
            const int t = (TT);                                               \
            int pos = b0 + t;                                                 \
            if (t >= c1) pos = b1 + t;                                        \
            if (t >= c2) pos = b2 + t;                                        \
            if (t >= c3) pos = b3 + t;                                        \
            long long raw = 0;                                                \
            if (t < m)                                                        \
                raw = __builtin_nontemporal_load((const long long*)(bins + pos)); \
            XX = (int)raw;                                                    \
            VV = __int_as_float((int)(raw >> 32));                            \
            SS = (t < c2) ? nvoff : 0u; }
        SLOT(T,      x0, v0, so0)
        SLOT(T + 8,  x1, v1, so1)
        SLOT(T + 16, x2, v2, so2)
        SLOT(T + 24, x3, v3, so3)
        #undef SLOT
        const uint4 w0 = *(const uint4*)(base + (so0 + ((u32)x0 & 0xFFFFFFC0u) + (u32)dsub));
        const uint4 w1 = *(const uint4*)(base + (so1 + ((u32)x1 & 0xFFFFFFC0u) + (u32)dsub));
        const uint4 w2 = *(const uint4*)(base + (so2 + ((u32)x2 & 0xFFFFFFC0u) + (u32)dsub));
        const uint4 w3 = *(const uint4*)(base + (so3 + ((u32)x3 & 0xFFFFFFC0u) + (u32)dsub));
        #define FMA8(W, V) {                                                  \
            acc[0] = fmaf((V), __int_as_float((W).x << 16),         acc[0]);  \
            acc[1] = fmaf((V), __int_as_float((W).x & 0xffff0000u), acc[1]);  \
            acc[2] = fmaf((V), __int_as_float((W).y << 16),         acc[2]);  \
            acc[3] = fmaf((V), __int_as_float((W).y & 0xffff0000u), acc[3]);  \
            acc[4] = fmaf((V), __int_as_float((W).z << 16),         acc[4]);  \
            acc[5] = fmaf((V), __int_as_float((W).z & 0xffff0000u), acc[5]);  \
            acc[6] = fmaf((V), __int_as_float((W).w << 16),         acc[6]);  \
            acc[7] = fmaf((V), __int_as_float((W).w & 0xffff0000u), acc[7]); }
        FMA8(w0, v0)
        FMA8(w1, v1)
        FMA8(w2, v2)
        FMA8(w3, v3)
        #undef FMA8
    }
}

__device__ __forceinline__ void reduce_groups8(float acc[8]) {
    #pragma unroll
    for (int d = 0; d < 8; ++d) {
        acc[d] += __shfl_xor(acc[d], 8);
        acc[d] += __shfl_xor(acc[d], 16);
        acc[d] += __shfl_xor(acc[d], 32);
    }
}

// s1 = bf16(0.5*(A[i0]+A[i1]) @ s0)
__global__ __launch_bounds__(256) void gather_op_kernel(
    const u16* __restrict__ s0, u16* __restrict__ dst,
    const int2* __restrict__ bins, const int2* __restrict__ rowinfo,
    const int* __restrict__ idx) {
    const int lane = threadIdx.x & 63;
    const int row  = blockIdx.x * 4 + (threadIdx.x >> 6);
    const int grp  = lane >> 3;
    const int sub  = lane & 7;
    const int dsub = sub << 3;
    int2 i0 = rowinfo[idx[0] * N_NODES + row]; i0.x -= i0.y;   // end -> start
    int2 i1 = rowinfo[idx[1] * N_NODES + row]; i1.x -= i1.y;
    const int2 iz = make_int2(0, 0);
    float acc[8] = {0.f, 0.f, 0.f, 0.f, 0.f, 0.f, 0.f, 0.f};
    gather4(s0, 0u, bins, i0, i1, iz, iz, grp, dsub, acc);
    reduce_groups8(acc);
    if (grp == 0) {
        u32 p[4];
        #pragma unroll
        for (int q = 0; q < 4; ++q) {
            __hip_bfloat16 blo = __float2bfloat16(0.5f * acc[2 * q]);
            __hip_bfloat16 bhi = __float2bfloat16(0.5f * acc[2 * q + 1]);
            p[q] = (u32)(*(u16*)&blo) | ((u32)(*(u16*)&bhi) << 16);
        }
        *(uint4*)(dst + (long)row * DIM + dsub) = make_uint4(p[0], p[1], p[2], p[3]);
    }
}

// out = gelu(LN(0.5*(seq@s1) + 0.5*(res@s0)))
__global__ __launch_bounds__(256) void fused_op_ln_gelu_kernel(
    const u16* __restrict__ s0, float* __restrict__ out,
    const int2* __restrict__ bins, const int2* __restrict__ rowinfo,
    const int* __restrict__ idx_seq1, const int* __restrict__ idx_res,
    const float* __restrict__ gamma, const float* __restrict__ beta) {
    const int lane = threadIdx.x & 63;
    const int row  = blockIdx.x * 4 + (threadIdx.x >> 6);
    const int grp  = lane >> 3;
    const int sub  = lane & 7;
    const int dsub = sub << 3;
    // segments 0,1 gather from s1 (= s0 + NVOFF via nvoff), 2,3 from s0
    int2 i0 = rowinfo[idx_seq1[0] * N_NODES + row]; i0.x -= i0.y;
    int2 i1 = rowinfo[idx_seq1[1] * N_NODES + row]; i1.x -= i1.y;
    int2 i2 = rowinfo[idx_res[0]  * N_NODES + row]; i2.x -= i2.y;
    int2 i3 = rowinfo[idx_res[1]  * N_NODES + row]; i3.x -= i3.y;
    float acc[8] = {0.f, 0.f, 0.f, 0.f, 0.f, 0.f, 0.f, 0.f};
    gather4(s0, NVOFF, bins, i0, i1, i2, i3, grp, dsub, acc);
    reduce_groups8(acc);
    #pragma unroll
    for (int d = 0; d < 8; ++d) acc[d] *= 0.5f;
    float s = 0.f, s2 = 0.f;
    #pragma unroll
    for (int d = 0; d < 8; ++d) { s += acc[d]; s2 += acc[d] * acc[d]; }
    s  += __shfl_xor(s, 1);  s  += __shfl_xor(s, 2);  s  += __shfl_xor(s, 4);
    s2 += __shfl_xor(s2, 1); s2 += __shfl_xor(s2, 2); s2 += __shfl_xor(s2, 4);
    const float mu  = s * (1.0f / DIM);
    const float var = s2 * (1.0f / DIM) - mu * mu;
    const float inv = rsqrtf(var + 1e-5f);
    if (grp == 0) {
        const float4 gm0 = ((const float4*)gamma)[sub * 2];
        const float4 gm1 = ((const float4*)gamma)[sub * 2 + 1];
        const float4 bt0 = ((const float4*)beta)[sub * 2];
        const float4 bt1 = ((const float4*)beta)[sub * 2 + 1];
        float y[8];
        y[0] = (acc[0] - mu) * inv * gm0.x + bt0.x;
        y[1] = (acc[1] - mu) * inv * gm0.y + bt0.y;
        y[2] = (acc[2] - mu) * inv * gm0.z + bt0.z;
        y[3] = (acc[3] - mu) * inv * gm0.w + bt0.w;
        y[4] = (acc[4] - mu) * inv * gm1.x + bt1.x;
        y[5] = (acc[5] - mu) * inv * gm1.y + bt1.y;
        y[6] = (acc[6] - mu) * inv * gm1.z + bt1.z;
        y[7] = (acc[7] - mu) * inv * gm1.w + bt1.w;
        float4 o0, o1;
        o0.x = 0.5f * y[0] * (1.0f + erff(y[0] * 0.70710678118654752f));
        o0.y = 0.5f * y[1] * (1.0f + erff(y[1] * 0.70710678118654752f));
        o0.z = 0.5f * y[2] * (1.0f + erff(y[2] * 0.70710678118654752f));
        o0.w = 0.5f * y[3] * (1.0f + erff(y[3] * 0.70710678118654752f));
        o1.x = 0.5f * y[4] * (1.0f + erff(y[4] * 0.70710678118654752f));
        o1.y = 0.5f * y[5] * (1.0f + erff(y[5] * 0.70710678118654752f));
        o1.z = 0.5f * y[6] * (1.0f + erff(y[6] * 0.70710678118654752f));
        o1.w = 0.5f * y[7] * (1.0f + erff(y[7] * 0.70710678118654752f));
        float4* po = (float4*)(out + (long)row * DIM + dsub);
        po[0] = o0;
        po[1] = o1;
    }
}

extern "C" void kernel_launch(void* const* d_in, const int* in_sizes, int n_in,
                              void* d_out, int out_size, void* d_ws, size_t ws_size,
                              hipStream_t stream) {
    const float* x     = (const float*)d_in[0];
    const float* W     = (const float*)d_in[1];
    const float* b     = (const float*)d_in[2];
    const int*   rows  = (const int*)d_in[3];
    const int*   cols  = (const int*)d_in[4];
    const float* vals  = (const float*)d_in[5];
    const float* gamma = (const float*)d_in[6];
    const float* beta  = (const float*)d_in[7];
    const int*   idxes_seq = (const int*)d_in[8];   // [2,2] flat
    const int*   idxes_res = (const int*)d_in[9];   // [1,2] flat
    float* out = (float*)d_out;

    // workspace layout: ~82 MB total
    int2*  bins    = (int2*)d_ws;                                // 4E int2 = 51.2 MB
    u16*   s0      = (u16*)(bins + (size_t)N_ADJ * E_EDGES);     // 12.8 MB bf16
    u16*   s1      = s0 + (size_t)N_NODES * DIM;                 // 12.8 MB bf16 (= s0 + NVOFF)
    int2*  rowinfo = (int2*)(s1 + (size_t)N_NODES * DIM);        // 3.2 MB
    int*   gcnt    = (int*)(rowinfo + (size_t)NROWTOT);          // 1.6 MB
    int*   psum    = gcnt + NROWTOT;                             // NCHUNKS ints
    int*   used    = psum + NCHUNKS;                             // 4 ints

    hipMemsetAsync(gcnt, 0, (size_t)NROWTOT * sizeof(int), stream);

    mask_kernel<<<1, 64, 0, stream>>>(idxes_seq, idxes_res, used);
    gemm_kernel<<<N_NODES / 16, 256, 0, stream>>>(x, W, b, s0);

    dim3 egrid(P1_GRIDX, N_ADJ);
    rowhist_kernel<<<egrid, P1_BLK, 0, stream>>>(rows, gcnt, used);
    scanA_kernel<<<NCHUNKS, 1024, 0, stream>>>(gcnt, psum);
    scanB_kernel<<<1, 512, 0, stream>>>(psum);
    scanC_kernel<<<NCHUNKS, 1024, 0, stream>>>(gcnt, psum, rowinfo);
    place_kernel<<<egrid, P1_BLK, 0, stream>>>(rows, cols, vals,
                                               (int*)rowinfo, bins, used);

    // s1 = 0.5*(A[i0]+A[i1]) @ s0
    gather_op_kernel<<<N_NODES / 4, 256, 0, stream>>>(s0, s1, bins, rowinfo, idxes_seq);
    // out = gelu(LN(0.5*(A[i2]+A[i3])@s1 + 0.5*(A[r0]+A[r1])@s0))
    fused_op_ln_gelu_kernel<<<N_NODES / 4, 256, 0, stream>>>(
        s0, out, bins, rowinfo, idxes_seq + 2, idxes_res, gamma, beta);
}

// Round 7
// 411.332 us; speedup vs baseline: 9.4025x; 1.7475x over previous
//
#include <hip/hip_runtime.h>
#include <hip/hip_bf16.h>
#include <math.h>

#define N_NODES 100000
#define DIM 64
#define E_EDGES 1600000
#define N_ADJ 4
#define NB 391               // ceil(100000/256) buckets of 256 rows
#define NBTOT (N_ADJ * NB)   // 1564
#define P1_BLK 1024
#define P1_CHUNK 12800
#define P1_GRIDX 125         // 125 * 12800 = 1.6M
#define SORT_STAGE 6144      // per-bucket LDS stage; mean load 4096, +32 sigma
#define NVOFF ((u32)N_NODES * DIM)   // u16 elements between s0 and s1

typedef unsigned short u16;
typedef unsigned int u32;

// ---- used-adjacency mask from device-side idxes ----
__global__ void mask_kernel(const int* __restrict__ iseq,
                            const int* __restrict__ ires,
                            int* __restrict__ used) {
    if (threadIdx.x == 0) {
        used[0] = used[1] = used[2] = used[3] = 0;
        used[iseq[0]] = 1; used[iseq[1]] = 1;
        used[iseq[2]] = 1; used[iseq[3]] = 1;
        used[ires[0]] = 1; used[ires[1]] = 1;
    }
}

// ---------------- GEMM: s0 = bf16(x @ W + b) ----------------
__global__ __launch_bounds__(256) void gemm_kernel(
    const float* __restrict__ x, const float* __restrict__ W,
    const float* __restrict__ b, u16* __restrict__ h) {
    __shared__ float Ws[DIM * DIM];
    __shared__ float xs[16 * DIM];
    const int tid = threadIdx.x;
    const long row0 = (long)blockIdx.x * 16;
    for (int i = tid; i < DIM * DIM; i += 256) Ws[i] = W[i];
    for (int i = tid; i < 16 * DIM; i += 256) xs[i] = x[row0 * DIM + i];
    __syncthreads();
    const int lane = tid & 63;
    const int grp  = tid >> 6;
    const float bias = b[lane];
    #pragma unroll
    for (int rr = 0; rr < 4; ++rr) {
        const int r = grp * 4 + rr;
        float acc = bias;
        #pragma unroll
        for (int k = 0; k < DIM; ++k)
            acc += xs[r * DIM + k] * Ws[k * DIM + lane];
        __hip_bfloat16 hb = __float2bfloat16(acc);
        h[(row0 + r) * DIM + lane] = *(u16*)&hb;
    }
}

// ---- hist: LDS-aggregated 256-row-bucket counts -> gcnt ----
__global__ __launch_bounds__(1024) void hist_kernel(
    const int* __restrict__ rows, int* __restrict__ gcnt,
    const int* __restrict__ used) {
    __shared__ int h[NB];
    const int a = blockIdx.y;
    if (!used[a]) return;
    const int tid = threadIdx.x;
    const long e0 = (long)a * E_EDGES + (long)blockIdx.x * P1_CHUNK;
    for (int i = tid; i < NB; i += P1_BLK) h[i] = 0;
    __syncthreads();
    for (int i = tid; i < P1_CHUNK; i += P1_BLK)
        atomicAdd(&h[rows[e0 + i] >> 8], 1);
    __syncthreads();
    for (int bk = tid; bk < NB; bk += P1_BLK) {
        const int c = h[bk];
        if (c) atomicAdd(&gcnt[a * NB + bk], c);
    }
}

// ---- scan: exact exclusive scan of 1564 bucket counts (1 block) ----
__global__ __launch_bounds__(1024) void scan_kernel(
    const int* __restrict__ gcnt, int* __restrict__ bbase,
    int* __restrict__ cursor) {
    __shared__ int wsum[16];
    const int tid = threadIdx.x, lane = tid & 63, wave = tid >> 6;
    int pre[2];
    int tsum = 0;
    #pragma unroll
    for (int k = 0; k < 2; ++k) {
        const int idx = tid * 2 + k;
        const int v = (idx < NBTOT) ? gcnt[idx] : 0;
        pre[k] = tsum;
        tsum += v;
    }
    int incl = tsum;
    #pragma unroll
    for (int o = 1; o < 64; o <<= 1) {
        const int t = __shfl_up(incl, o);
        if (lane >= o) incl += t;
    }
    if (lane == 63) wsum[wave] = incl;
    __syncthreads();
    if (tid == 0) {
        int run = 0;
        #pragma unroll
        for (int w = 0; w < 16; ++w) { const int t = wsum[w]; wsum[w] = run; run += t; }
    }
    __syncthreads();
    const int texcl = incl - tsum + wsum[wave];
    #pragma unroll
    for (int k = 0; k < 2; ++k) {
        const int idx = tid * 2 + k;
        if (idx < NBTOT) {
            const int v = texcl + pre[k];
            bbase[idx]  = v;
            cursor[idx] = v;
        }
    }
    if (tid == 0) bbase[NBTOT] = N_ADJ * E_EDGES;
}

// ---- place: reserve per-(block,bucket) runs, pack edges ----
// Record = (col<<8 | r&255, val); ~33-edge (264 B) contiguous runs per
// (block,bucket) keep write amplification near 1.
__global__ __launch_bounds__(1024) void place_kernel(
    const int* __restrict__ rows, const int* __restrict__ cols,
    const float* __restrict__ vals, int* __restrict__ cursor,
    int2* __restrict__ bins, const int* __restrict__ used) {
    __shared__ int h[NB];
    const int a = blockIdx.y;
    if (!used[a]) return;
    const int tid = threadIdx.x;
    const long e0 = (long)a * E_EDGES + (long)blockIdx.x * P1_CHUNK;
    for (int i = tid; i < NB; i += P1_BLK) h[i] = 0;
    __syncthreads();
    for (int i = tid; i < P1_CHUNK; i += P1_BLK)
        atomicAdd(&h[rows[e0 + i] >> 8], 1);
    __syncthreads();
    for (int bk = tid; bk < NB; bk += P1_BLK) {
        const int c = h[bk];
        if (c) h[bk] = atomicAdd(&cursor[a * NB + bk], c);  // abs base of run
    }
    __syncthreads();
    for (int i = tid; i < P1_CHUNK; i += P1_BLK) {
        const int r  = rows[e0 + i];
        const int bk = r >> 8;
        const int slot = atomicAdd(&h[bk], 1);              // absolute bins index
        bins[slot] = make_int2((cols[e0 + i] << 8) | (r & 255),
                               __float_as_int(vals[e0 + i]));
    }
}

// ---- sort: per-bucket counting sort by r&255, emit per-row (start,count);
//      records rewritten to (col<<6, val) so consumers match round-2 core ----
__global__ __launch_bounds__(256) void sort_kernel(
    int2* __restrict__ bins, const int* __restrict__ bbase,
    int2* __restrict__ rowinfo, const int* __restrict__ used) {
    __shared__ int2 stage[SORT_STAGE];
    __shared__ int h[256], off[256], cur[256], wsc[4];
    const int a   = blockIdx.x / NB;
    if (!used[a]) return;
    const int tid = threadIdx.x;
    const int bk  = blockIdx.x % NB;
    const int p0  = bbase[blockIdx.x];
    const int n   = min(bbase[blockIdx.x + 1] - p0, SORT_STAGE);

    h[tid] = 0;
    __syncthreads();
    for (int i = tid; i < n; i += 256) {
        const int2 e = bins[p0 + i];
        stage[i] = e;
        atomicAdd(&h[e.x & 255], 1);
    }
    __syncthreads();
    {
        const int lane = tid & 63, wave = tid >> 6;
        const int v = h[tid];
        int incl = v;
        #pragma unroll
        for (int o = 1; o < 64; o <<= 1) {
            const int t = __shfl_up(incl, o);
            if (lane >= o) incl += t;
        }
        if (lane == 63) wsc[wave] = incl;
        __syncthreads();
        if (tid == 0) {
            int run = 0;
            #pragma unroll
            for (int w = 0; w < 4; ++w) { const int t = wsc[w]; wsc[w] = run; run += t; }
        }
        __syncthreads();
        const int e = incl - v + wsc[wave];
        off[tid] = e;
        cur[tid] = e;
    }
    __syncthreads();
    for (int i = tid; i < n; i += 256) {
        const int2 e = stage[i];
        const int rank = atomicAdd(&cur[e.x & 255], 1);
        bins[p0 + rank] = make_int2(((u32)e.x >> 8) << 6, e.y);
    }
    {
        const int row = (bk << 8) + tid;
        if (row < N_NODES)
            rowinfo[a * N_NODES + row] = make_int2(p0 + off[tid], h[tid]);
    }
}

// ---------------- Pull gather core (round-2 structure, verbatim) ----------
// Wave = 1 row. 8 groups of 8 lanes; each edge's 64-dim bf16 row (128 B)
// loaded by 8 lanes as dwordx4. The 4 edge segments are virtually
// concatenated into t in [0, m); cascaded selects map t -> bins position
// and source offset. 4 slots deep per lane => 32 edges in flight.
__device__ __forceinline__ void gather4(
    const u16* __restrict__ base, const u32 nvoff,
    const int2* __restrict__ bins,
    const int2 i0, const int2 i1, const int2 i2, const int2 i3,
    const int grp, const int dsub, float acc[8])
{
    const int c1 = i0.y;
    const int c2 = c1 + i1.y;
    const int c3 = c2 + i2.y;
    const int m  = c3 + i3.y;
    const int b0 = i0.x;
    const int b1 = i1.x - c1;
    const int b2 = i2.x - c2;
    const int b3 = i3.x - c3;

    for (int T = grp; T < m; T += 32) {
        int x0, x1, x2, x3;
        float v0, v1, v2, v3;
        u32 so0, so1, so2, so3;
        #define SLOT(TT, XX, VV, SS) {                                        \
            const int t = (TT);                                               \
            int pos = b0 + t;                                                 \
            if (t >= c1) pos = b1 + t;                                        \
            if (t >= c2) pos = b2 + t;                                        \
            if (t >= c3) pos = b3 + t;                                        \
            long long raw = 0;                                                \
            if (t < m)                                                        \
                raw = __builtin_nontemporal_load((const long long*)(bins + pos)); \
            XX = (int)raw;                                                    \
            VV = __int_as_float((int)(raw >> 32));                            \
            SS = (t < c2) ? nvoff : 0u; }
        SLOT(T,      x0, v0, so0)
        SLOT(T + 8,  x1, v1, so1)
        SLOT(T + 16, x2, v2, so2)
        SLOT(T + 24, x3, v3, so3)
        #undef SLOT
        const uint4 w0 = *(const uint4*)(base + (so0 + ((u32)x0 & 0xFFFFFFC0u) + (u32)dsub));
        const uint4 w1 = *(const uint4*)(base + (so1 + ((u32)x1 & 0xFFFFFFC0u) + (u32)dsub));
        const uint4 w2 = *(const uint4*)(base + (so2 + ((u32)x2 & 0xFFFFFFC0u) + (u32)dsub));
        const uint4 w3 = *(const uint4*)(base + (so3 + ((u32)x3 & 0xFFFFFFC0u) + (u32)dsub));
        #define FMA8(W, V) {                                                  \
            acc[0] = fmaf((V), __int_as_float((W).x << 16),         acc[0]);  \
            acc[1] = fmaf((V), __int_as_float((W).x & 0xffff0000u), acc[1]);  \
            acc[2] = fmaf((V), __int_as_float((W).y << 16),         acc[2]);  \
            acc[3] = fmaf((V), __int_as_float((W).y & 0xffff0000u), acc[3]);  \
            acc[4] = fmaf((V), __int_as_float((W).z << 16),         acc[4]);  \
            acc[5] = fmaf((V), __int_as_float((W).z & 0xffff0000u), acc[5]);  \
            acc[6] = fmaf((V), __int_as_float((W).w << 16),         acc[6]);  \
            acc[7] = fmaf((V), __int_as_float((W).w & 0xffff0000u), acc[7]); }
        FMA8(w0, v0)
        FMA8(w1, v1)
        FMA8(w2, v2)
        FMA8(w3, v3)
        #undef FMA8
    }
}

__device__ __forceinline__ void reduce_groups8(float acc[8]) {
    #pragma unroll
    for (int d = 0; d < 8; ++d) {
        acc[d] += __shfl_xor(acc[d], 8);
        acc[d] += __shfl_xor(acc[d], 16);
        acc[d] += __shfl_xor(acc[d], 32);
    }
}

// s1 = bf16(0.5*(A[i0]+A[i1]) @ s0)
__global__ __launch_bounds__(256) void gather_op_kernel(
    const u16* __restrict__ s0, u16* __restrict__ dst,
    const int2* __restrict__ bins, const int2* __restrict__ rowinfo,
    const int* __restrict__ idx) {
    const int lane = threadIdx.x & 63;
    const int row  = blockIdx.x * 4 + (threadIdx.x >> 6);
    const int grp  = lane >> 3;
    const int sub  = lane & 7;
    const int dsub = sub << 3;
    const int2 i0 = rowinfo[idx[0] * N_NODES + row];
    const int2 i1 = rowinfo[idx[1] * N_NODES + row];
    const int2 iz = make_int2(0, 0);
    float acc[8] = {0.f, 0.f, 0.f, 0.f, 0.f, 0.f, 0.f, 0.f};
    gather4(s0, 0u, bins, i0, i1, iz, iz, grp, dsub, acc);
    reduce_groups8(acc);
    if (grp == 0) {
        u32 p[4];
        #pragma unroll
        for (int q = 0; q < 4; ++q) {
            __hip_bfloat16 blo = __float2bfloat16(0.5f * acc[2 * q]);
            __hip_bfloat16 bhi = __float2bfloat16(0.5f * acc[2 * q + 1]);
            p[q] = (u32)(*(u16*)&blo) | ((u32)(*(u16*)&bhi) << 16);
        }
        *(uint4*)(dst + (long)row * DIM + dsub) = make_uint4(p[0], p[1], p[2], p[3]);
    }
}

// out = gelu(LN(0.5*(seq@s1) + 0.5*(res@s0)))
__global__ __launch_bounds__(256) void fused_op_ln_gelu_kernel(
    const u16* __restrict__ s0, float* __restrict__ out,
    const int2* __restrict__ bins, const int2* __restrict__ rowinfo,
    const int* __restrict__ idx_seq1, const int* __restrict__ idx_res,
    const float* __restrict__ gamma, const float* __restrict__ beta) {
    const int lane = threadIdx.x & 63;
    const int row  = blockIdx.x * 4 + (threadIdx.x >> 6);
    const int grp  = lane >> 3;
    const int sub  = lane & 7;
    const int dsub = sub << 3;
    // segments 0,1 gather from s1 (= s0 + NVOFF via nvoff), 2,3 from s0
    const int2 i0 = rowinfo[idx_seq1[0] * N_NODES + row];
    const int2 i1 = rowinfo[idx_seq1[1] * N_NODES + row];
    const int2 i2 = rowinfo[idx_res[0]  * N_NODES + row];
    const int2 i3 = rowinfo[idx_res[1]  * N_NODES + row];
    float acc[8] = {0.f, 0.f, 0.f, 0.f, 0.f, 0.f, 0.f, 0.f};
    gather4(s0, NVOFF, bins, i0, i1, i2, i3, grp, dsub, acc);
    reduce_groups8(acc);
    #pragma unroll
    for (int d = 0; d < 8; ++d) acc[d] *= 0.5f;
    float s = 0.f, s2 = 0.f;
    #pragma unroll
    for (int d = 0; d < 8; ++d) { s += acc[d]; s2 += acc[d] * acc[d]; }
    s  += __shfl_xor(s, 1);  s  += __shfl_xor(s, 2);  s  += __shfl_xor(s, 4);
    s2 += __shfl_xor(s2, 1); s2 += __shfl_xor(s2, 2); s2 += __shfl_xor(s2, 4);
    const float mu  = s * (1.0f / DIM);
    const float var = s2 * (1.0f / DIM) - mu * mu;
    const float inv = rsqrtf(var + 1e-5f);
    if (grp == 0) {
        const float4 gm0 = ((const float4*)gamma)[sub * 2];
        const float4 gm1 = ((const float4*)gamma)[sub * 2 + 1];
        const float4 bt0 = ((const float4*)beta)[sub * 2];
        const float4 bt1 = ((const float4*)beta)[sub * 2 + 1];
        float y[8];
        y[0] = (acc[0] - mu) * inv * gm0.x + bt0.x;
        y[1] = (acc[1] - mu) * inv * gm0.y + bt0.y;
        y[2] = (acc[2] - mu) * inv * gm0.z + bt0.z;
        y[3] = (acc[3] - mu) * inv * gm0.w + bt0.w;
        y[4] = (acc[4] - mu) * inv * gm1.x + bt1.x;
        y[5] = (acc[5] - mu) * inv * gm1.y + bt1.y;
        y[6] = (acc[6] - mu) * inv * gm1.z + bt1.z;
        y[7] = (acc[7] - mu) * inv * gm1.w + bt1.w;
        float4 o0, o1;
        o0.x = 0.5f * y[0] * (1.0f + erff(y[0] * 0.70710678118654752f));
        o0.y = 0.5f * y[1] * (1.0f + erff(y[1] * 0.70710678118654752f));
        o0.z = 0.5f * y[2] * (1.0f + erff(y[2] * 0.70710678118654752f));
        o0.w = 0.5f * y[3] * (1.0f + erff(y[3] * 0.70710678118654752f));
        o1.x = 0.5f * y[4] * (1.0f + erff(y[4] * 0.70710678118654752f));
        o1.y = 0.5f * y[5] * (1.0f + erff(y[5] * 0.70710678118654752f));
        o1.z = 0.5f * y[6] * (1.0f + erff(y[6] * 0.70710678118654752f));
        o1.w = 0.5f * y[7] * (1.0f + erff(y[7] * 0.70710678118654752f));
        float4* po = (float4*)(out + (long)row * DIM + dsub);
        po[0] = o0;
        po[1] = o1;
    }
}

extern "C" void kernel_launch(void* const* d_in, const int* in_sizes, int n_in,
                              void* d_out, int out_size, void* d_ws, size_t ws_size,
                              hipStream_t stream) {
    const float* x     = (const float*)d_in[0];
    const float* W     = (const float*)d_in[1];
    const float* b     = (const float*)d_in[2];
    const int*   rows  = (const int*)d_in[3];
    const int*   cols  = (const int*)d_in[4];
    const float* vals  = (const float*)d_in[5];
    const float* gamma = (const float*)d_in[6];
    const float* beta  = (const float*)d_in[7];
    const int*   idxes_seq = (const int*)d_in[8];   // [2,2] flat
    const int*   idxes_res = (const int*)d_in[9];   // [1,2] flat
    float* out = (float*)d_out;

    // workspace layout: ~80 MB total
    int2*  bins    = (int2*)d_ws;                                // 4E int2 = 51.2 MB
    u16*   s0      = (u16*)(bins + (size_t)N_ADJ * E_EDGES);     // 12.8 MB bf16
    u16*   s1      = s0 + (size_t)N_NODES * DIM;                 // 12.8 MB bf16 (= s0 + NVOFF)
    int2*  rowinfo = (int2*)(s1 + (size_t)N_NODES * DIM);        // 3.2 MB
    int*   gcnt    = (int*)(rowinfo + (size_t)N_ADJ * N_NODES);  // 1564 ints
    int*   bbase   = gcnt + NBTOT;                               // 1565 ints
    int*   cursor  = bbase + NBTOT + 1;                          // 1564 ints
    int*   used    = cursor + NBTOT;                             // 4 ints

    hipMemsetAsync(gcnt, 0, (size_t)NBTOT * sizeof(int), stream);

    mask_kernel<<<1, 64, 0, stream>>>(idxes_seq, idxes_res, used);
    gemm_kernel<<<N_NODES / 16, 256, 0, stream>>>(x, W, b, s0);

    dim3 egrid(P1_GRIDX, N_ADJ);
    hist_kernel <<<egrid, P1_BLK, 0, stream>>>(rows, gcnt, used);
    scan_kernel <<<1, P1_BLK, 0, stream>>>(gcnt, bbase, cursor);
    place_kernel<<<egrid, P1_BLK, 0, stream>>>(rows, cols, vals, cursor, bins, used);
    sort_kernel <<<NBTOT, 256, 0, stream>>>(bins, bbase, rowinfo, used);

    // s1 = 0.5*(A[i0]+A[i1]) @ s0
    gather_op_kernel<<<N_NODES / 4, 256, 0, stream>>>(s0, s1, bins, rowinfo, idxes_seq);
    // out = gelu(LN(0.5*(A[i2]+A[i3])@s1 + 0.5*(A[r0]+A[r1])@s0))
    fused_op_ln_gelu_kernel<<<N_NODES / 4, 256, 0, stream>>>(
        s0, out, bins, rowinfo, idxes_seq + 2, idxes_res, gamma, beta);
}

// Round 9
// 398.853 us; speedup vs baseline: 9.6966x; 1.0313x over previous
//
#include <hip/hip_runtime.h>
#include <hip/hip_bf16.h>
#include <math.h>

#define N_NODES 100000
#define DIM 64
#define E_EDGES 1600000
#define N_ADJ 4
#define NB 391               // ceil(100000/256) buckets of 256 rows
#define NBTOT (N_ADJ * NB)   // 1564
#define P1_BLK 1024
#define P1_CHUNK 12800
#define P1_GRIDX 125         // 125 * 12800 = 1.6M
#define CAP 5120             // fixed-cap slots/bucket: mean 4096 + 16 sigma
#define SORT_STAGE 5120      // per-bucket LDS stage (40 KB)
#define NVOFF ((u32)N_NODES * DIM)   // u16 elements between s0 and s1

typedef unsigned short u16;
typedef unsigned int u32;
typedef float f32x4 __attribute__((ext_vector_type(4)));   // native vec for nt-store

// ---- init: used-mask + gcnt zero + (fixed-cap) computed bbase/cursor ----
__global__ __launch_bounds__(1024) void mask_init_kernel(
    const int* __restrict__ iseq, const int* __restrict__ ires,
    int* __restrict__ used, int* __restrict__ gcnt,
    int* __restrict__ bbase, int* __restrict__ cursor, const int mode) {
    const int tid = threadIdx.x;
    for (int k = tid; k < NBTOT; k += 1024) {
        gcnt[k] = 0;
        if (mode) { bbase[k] = k * CAP; cursor[k] = k * CAP; }
    }
    if (tid == 0) {
        if (mode) bbase[NBTOT] = NBTOT * CAP;
        used[0] = used[1] = used[2] = used[3] = 0;
        used[iseq[0]] = 1; used[iseq[1]] = 1;
        used[iseq[2]] = 1; used[iseq[3]] = 1;
        used[ires[0]] = 1; used[ires[1]] = 1;
    }
}

// ---------------- GEMM: s0 = bf16(x @ W + b) ----------------
__global__ __launch_bounds__(256) void gemm_kernel(
    const float* __restrict__ x, const float* __restrict__ W,
    const float* __restrict__ b, u16* __restrict__ h) {
    __shared__ float Ws[DIM * DIM];
    __shared__ float xs[16 * DIM];
    const int tid = threadIdx.x;
    const long row0 = (long)blockIdx.x * 16;
    for (int i = tid; i < DIM * DIM; i += 256) Ws[i] = W[i];
    for (int i = tid; i < 16 * DIM; i += 256) xs[i] = x[row0 * DIM + i];
    __syncthreads();
    const int lane = tid & 63;
    const int grp  = tid >> 6;
    const float bias = b[lane];
    #pragma unroll
    for (int rr = 0; rr < 4; ++rr) {
        const int r = grp * 4 + rr;
        float acc = bias;
        #pragma unroll
        for (int k = 0; k < DIM; ++k)
            acc += xs[r * DIM + k] * Ws[k * DIM + lane];
        __hip_bfloat16 hb = __float2bfloat16(acc);
        h[(row0 + r) * DIM + lane] = *(u16*)&hb;
    }
}

// ---- hist (dense fallback only): bucket counts -> gcnt ----
__global__ __launch_bounds__(1024) void hist_kernel(
    const int* __restrict__ rows, int* __restrict__ gcnt,
    const int* __restrict__ used) {
    __shared__ int h[NB];
    const int a = blockIdx.y;
    if (!used[a]) return;
    const int tid = threadIdx.x;
    const long e0 = (long)a * E_EDGES + (long)blockIdx.x * P1_CHUNK;
    for (int i = tid; i < NB; i += P1_BLK) h[i] = 0;
    __syncthreads();
    for (int i = tid; i < P1_CHUNK; i += P1_BLK)
        atomicAdd(&h[rows[e0 + i] >> 8], 1);
    __syncthreads();
    for (int bk = tid; bk < NB; bk += P1_BLK) {
        const int c = h[bk];
        if (c) atomicAdd(&gcnt[a * NB + bk], c);
    }
}

// ---- scan (dense fallback only): exclusive scan of 1564 counts ----
__global__ __launch_bounds__(1024) void scan_kernel(
    const int* __restrict__ gcnt, int* __restrict__ bbase,
    int* __restrict__ cursor) {
    __shared__ int wsum[16];
    const int tid = threadIdx.x, lane = tid & 63, wave = tid >> 6;
    int pre[2];
    int tsum = 0;
    #pragma unroll
    for (int k = 0; k < 2; ++k) {
        const int idx = tid * 2 + k;
        const int v = (idx < NBTOT) ? gcnt[idx] : 0;
        pre[k] = tsum;
        tsum += v;
    }
    int incl = tsum;
    #pragma unroll
    for (int o = 1; o < 64; o <<= 1) {
        const int t = __shfl_up(incl, o);
        if (lane >= o) incl += t;
    }
    if (lane == 63) wsum[wave] = incl;
    __syncthreads();
    if (tid == 0) {
        int run = 0;
        #pragma unroll
        for (int w = 0; w < 16; ++w) { const int t = wsum[w]; wsum[w] = run; run += t; }
    }
    __syncthreads();
    const int texcl = incl - tsum + wsum[wave];
    #pragma unroll
    for (int k = 0; k < 2; ++k) {
        const int idx = tid * 2 + k;
        if (idx < NBTOT) {
            const int v = texcl + pre[k];
            bbase[idx]  = v;
            cursor[idx] = v;
        }
    }
    if (tid == 0) bbase[NBTOT] = N_ADJ * E_EDGES;
}

// ---- place: reserve per-(block,bucket) runs off preinit'd cursor, pack ----
// Record = (col<<8 | r&255, val). cap>0 clamps against bucket overflow
// (fixed-cap mode; probability ~0, correctness guard for OOB only).
__global__ __launch_bounds__(1024) void place_kernel(
    const int* __restrict__ rows, const int* __restrict__ cols,
    const float* __restrict__ vals, int* __restrict__ cursor,
    int2* __restrict__ bins, const int* __restrict__ used, const int cap) {
    __shared__ int h[NB];
    const int a = blockIdx.y;
    if (!used[a]) return;
    const int tid = threadIdx.x;
    const long e0 = (long)a * E_EDGES + (long)blockIdx.x * P1_CHUNK;
    for (int i = tid; i < NB; i += P1_BLK) h[i] = 0;
    __syncthreads();
    for (int i = tid; i < P1_CHUNK; i += P1_BLK)
        atomicAdd(&h[rows[e0 + i] >> 8], 1);
    __syncthreads();
    for (int bk = tid; bk < NB; bk += P1_BLK) {
        const int c = h[bk];
        if (c) h[bk] = atomicAdd(&cursor[a * NB + bk], c);  // abs base of run
    }
    __syncthreads();
    for (int i = tid; i < P1_CHUNK; i += P1_BLK) {
        const int r  = rows[e0 + i];
        const int bk = r >> 8;
        const int slot = atomicAdd(&h[bk], 1);              // absolute bins index
        if (!cap || slot < (a * NB + bk + 1) * cap)
            bins[slot] = make_int2((cols[e0 + i] << 8) | (r & 255),
                                   __float_as_int(vals[e0 + i]));
    }
}

// ---- sort: per-bucket counting sort by r&255, emit per-row (start,count);
//      n derived from cursor-bbase (works for dense AND fixed-cap);
//      records rewritten to (col<<6, val) for the gather core ----
__global__ __launch_bounds__(256) void sort_kernel(
    int2* __restrict__ bins, const int* __restrict__ bbase,
    const int* __restrict__ cursor, int2* __restrict__ rowinfo,
    const int* __restrict__ used) {
    __shared__ int2 stage[SORT_STAGE];
    __shared__ int h[256], off[256], cur[256], wsc[4];
    const int a   = blockIdx.x / NB;
    if (!used[a]) return;
    const int tid = threadIdx.x;
    const int bk  = blockIdx.x % NB;
    const int p0  = bbase[blockIdx.x];
    const int n   = min(cursor[blockIdx.x] - p0, SORT_STAGE);

    h[tid] = 0;
    __syncthreads();
    for (int i = tid; i < n; i += 256) {
        const int2 e = bins[p0 + i];
        stage[i] = e;
        atomicAdd(&h[e.x & 255], 1);
    }
    __syncthreads();
    {
        const int lane = tid & 63, wave = tid >> 6;
        const int v = h[tid];
        int incl = v;
        #pragma unroll
        for (int o = 1; o < 64; o <<= 1) {
            const int t = __shfl_up(incl, o);
            if (lane >= o) incl += t;
        }
        if (lane == 63) wsc[wave] = incl;
        __syncthreads();
        if (tid == 0) {
            int run = 0;
            #pragma unroll
            for (int w = 0; w < 4; ++w) { const int t = wsc[w]; wsc[w] = run; run += t; }
        }
        __syncthreads();
        const int e = incl - v + wsc[wave];
        off[tid] = e;
        cur[tid] = e;
    }
    __syncthreads();
    for (int i = tid; i < n; i += 256) {
        const int2 e = stage[i];
        const int rank = atomicAdd(&cur[e.x & 255], 1);
        bins[p0 + rank] = make_int2(((u32)e.x >> 8) << 6, e.y);
    }
    {
        const int row = (bk << 8) + tid;
        if (row < N_NODES)
            rowinfo[a * N_NODES + row] = make_int2(p0 + off[tid], h[tid]);
    }
}

// ---------------- Pull gather core (round-2 structure, verbatim) ----------
__device__ __forceinline__ void gather4(
    const u16* __restrict__ base, const u32 nvoff,
    const int2* __restrict__ bins,
    const int2 i0, const int2 i1, const int2 i2, const int2 i3,
    const int grp, const int dsub, float acc[8])
{
    const int c1 = i0.y;
    const int c2 = c1 + i1.y;
    const int c3 = c2 + i2.y;
    const int m  = c3 + i3.y;
    const int b0 = i0.x;
    const int b1 = i1.x - c1;
    const int b2 = i2.x - c2;
    const int b3 = i3.x - c3;

    for (int T = grp; T < m; T += 32) {
        int x0, x1, x2, x3;
        float v0, v1, v2, v3;
        u32 so0, so1, so2, so3;
        #define SLOT(TT, XX, VV, SS) {                                        \
            const int t = (TT);                                               \
            int pos = b0 + t;                                                 \
            if (t >= c1) pos = b1 + t;                                        \
            if (t >= c2) pos = b2 + t;                                        \
            if (t >= c3) pos = b3 + t;                                        \
            long long raw = 0;                                                \
            if (t < m)                                                        \
                raw = __builtin_nontemporal_load((const long long*)(bins + pos)); \
            XX = (int)raw;                                                    \
            VV = __int_as_float((int)(raw >> 32));                            \
            SS = (t < c2) ? nvoff : 0u; }
        SLOT(T,      x0, v0, so0)
        SLOT(T + 8,  x1, v1, so1)
        SLOT(T + 16, x2, v2, so2)
        SLOT(T + 24, x3, v3, so3)
        #undef SLOT
        const uint4 w0 = *(const uint4*)(base + (so0 + ((u32)x0 & 0xFFFFFFC0u) + (u32)dsub));
        const uint4 w1 = *(const uint4*)(base + (so1 + ((u32)x1 & 0xFFFFFFC0u) + (u32)dsub));
        const uint4 w2 = *(const uint4*)(base + (so2 + ((u32)x2 & 0xFFFFFFC0u) + (u32)dsub));
        const uint4 w3 = *(const uint4*)(base + (so3 + ((u32)x3 & 0xFFFFFFC0u) + (u32)dsub));
        #define FMA8(W, V) {                                                  \
            acc[0] = fmaf((V), __int_as_float((W).x << 16),         acc[0]);  \
            acc[1] = fmaf((V), __int_as_float((W).x & 0xffff0000u), acc[1]);  \
            acc[2] = fmaf((V), __int_as_float((W).y << 16),         acc[2]);  \
            acc[3] = fmaf((V), __int_as_float((W).y & 0xffff0000u), acc[3]);  \
            acc[4] = fmaf((V), __int_as_float((W).z << 16),         acc[4]);  \
            acc[5] = fmaf((V), __int_as_float((W).z & 0xffff0000u), acc[5]);  \
            acc[6] = fmaf((V), __int_as_float((W).w << 16),         acc[6]);  \
            acc[7] = fmaf((V), __int_as_float((W).w & 0xffff0000u), acc[7]); }
        FMA8(w0, v0)
        FMA8(w1, v1)
        FMA8(w2, v2)
        FMA8(w3, v3)
        #undef FMA8
    }
}

__device__ __forceinline__ void reduce_groups8(float acc[8]) {
    #pragma unroll
    for (int d = 0; d < 8; ++d) {
        acc[d] += __shfl_xor(acc[d], 8);
        acc[d] += __shfl_xor(acc[d], 16);
        acc[d] += __shfl_xor(acc[d], 32);
    }
}

// s1 = bf16(0.5*(A[i0]+A[i1]) @ s0)
__global__ __launch_bounds__(256) void gather_op_kernel(
    const u16* __restrict__ s0, u16* __restrict__ dst,
    const int2* __restrict__ bins, const int2* __restrict__ rowinfo,
    const int* __restrict__ idx) {
    const int lane = threadIdx.x & 63;
    const int row  = blockIdx.x * 4 + (threadIdx.x >> 6);
    const int grp  = lane >> 3;
    const int sub  = lane & 7;
    const int dsub = sub << 3;
    const int2 i0 = rowinfo[idx[0] * N_NODES + row];
    const int2 i1 = rowinfo[idx[1] * N_NODES + row];
    const int2 iz = make_int2(0, 0);
    float acc[8] = {0.f, 0.f, 0.f, 0.f, 0.f, 0.f, 0.f, 0.f};
    gather4(s0, 0u, bins, i0, i1, iz, iz, grp, dsub, acc);
    reduce_groups8(acc);
    if (grp == 0) {
        u32 p[4];
        #pragma unroll
        for (int q = 0; q < 4; ++q) {
            __hip_bfloat16 blo = __float2bfloat16(0.5f * acc[2 * q]);
            __hip_bfloat16 bhi = __float2bfloat16(0.5f * acc[2 * q + 1]);
            p[q] = (u32)(*(u16*)&blo) | ((u32)(*(u16*)&bhi) << 16);
        }
        *(uint4*)(dst + (long)row * DIM + dsub) = make_uint4(p[0], p[1], p[2], p[3]);
    }
}

// out = gelu(LN(0.5*(seq@s1) + 0.5*(res@s0)))
__global__ __launch_bounds__(256) void fused_op_ln_gelu_kernel(
    const u16* __restrict__ s0, float* __restrict__ out,
    const int2* __restrict__ bins, const int2* __restrict__ rowinfo,
    const int* __restrict__ idx_seq1, const int* __restrict__ idx_res,
    const float* __restrict__ gamma, const float* __restrict__ beta) {
    const int lane = threadIdx.x & 63;
    const int row  = blockIdx.x * 4 + (threadIdx.x >> 6);
    const int grp  = lane >> 3;
    const int sub  = lane & 7;
    const int dsub = sub << 3;
    // segments 0,1 gather from s1 (= s0 + NVOFF via nvoff), 2,3 from s0
    const int2 i0 = rowinfo[idx_seq1[0] * N_NODES + row];
    const int2 i1 = rowinfo[idx_seq1[1] * N_NODES + row];
    const int2 i2 = rowinfo[idx_res[0]  * N_NODES + row];
    const int2 i3 = rowinfo[idx_res[1]  * N_NODES + row];
    float acc[8] = {0.f, 0.f, 0.f, 0.f, 0.f, 0.f, 0.f, 0.f};
    gather4(s0, NVOFF, bins, i0, i1, i2, i3, grp, dsub, acc);
    reduce_groups8(acc);
    #pragma unroll
    for (int d = 0; d < 8; ++d) acc[d] *= 0.5f;
    float s = 0.f, s2 = 0.f;
    #pragma unroll
    for (int d = 0; d < 8; ++d) { s += acc[d]; s2 += acc[d] * acc[d]; }
    s  += __shfl_xor(s, 1);  s  += __shfl_xor(s, 2);  s  += __shfl_xor(s, 4);
    s2 += __shfl_xor(s2, 1); s2 += __shfl_xor(s2, 2); s2 += __shfl_xor(s2, 4);
    const float mu  = s * (1.0f / DIM);
    const float var = s2 * (1.0f / DIM) - mu * mu;
    const float inv = rsqrtf(var + 1e-5f);
    if (grp == 0) {
        const float4 gm0 = ((const float4*)gamma)[sub * 2];
        const float4 gm1 = ((const float4*)gamma)[sub * 2 + 1];
        const float4 bt0 = ((const float4*)beta)[sub * 2];
        const float4 bt1 = ((const float4*)beta)[sub * 2 + 1];
        float y[8];
        y[0] = (acc[0] - mu) * inv * gm0.x + bt0.x;
        y[1] = (acc[1] - mu) * inv * gm0.y + bt0.y;
        y[2] = (acc[2] - mu) * inv * gm0.z + bt0.z;
        y[3] = (acc[3] - mu) * inv * gm0.w + bt0.w;
        y[4] = (acc[4] - mu) * inv * gm1.x + bt1.x;
        y[5] = (acc[5] - mu) * inv * gm1.y + bt1.y;
        y[6] = (acc[6] - mu) * inv * gm1.z + bt1.z;
        y[7] = (acc[7] - mu) * inv * gm1.w + bt1.w;
        f32x4 o0, o1;
        o0.x = 0.5f * y[0] * (1.0f + erff(y[0] * 0.70710678118654752f));
        o0.y = 0.5f * y[1] * (1.0f + erff(y[1] * 0.70710678118654752f));
        o0.z = 0.5f * y[2] * (1.0f + erff(y[2] * 0.70710678118654752f));
        o0.w = 0.5f * y[3] * (1.0f + erff(y[3] * 0.70710678118654752f));
        o1.x = 0.5f * y[4] * (1.0f + erff(y[4] * 0.70710678118654752f));
        o1.y = 0.5f * y[5] * (1.0f + erff(y[5] * 0.70710678118654752f));
        o1.z = 0.5f * y[6] * (1.0f + erff(y[6] * 0.70710678118654752f));
        o1.w = 0.5f * y[7] * (1.0f + erff(y[7] * 0.70710678118654752f));
        // final output: never re-read -> nontemporal, keep L2 for gather tables
        f32x4* po = (f32x4*)(out + (long)row * DIM + dsub);
        __builtin_nontemporal_store(o0, po);
        __builtin_nontemporal_store(o1, po + 1);
    }
}

extern "C" void kernel_launch(void* const* d_in, const int* in_sizes, int n_in,
                              void* d_out, int out_size, void* d_ws, size_t ws_size,
                              hipStream_t stream) {
    const float* x     = (const float*)d_in[0];
    const float* W     = (const float*)d_in[1];
    const float* b     = (const float*)d_in[2];
    const int*   rows  = (const int*)d_in[3];
    const int*   cols  = (const int*)d_in[4];
    const float* vals  = (const float*)d_in[5];
    const float* gamma = (const float*)d_in[6];
    const float* beta  = (const float*)d_in[7];
    const int*   idxes_seq = (const int*)d_in[8];   // [2,2] flat
    const int*   idxes_res = (const int*)d_in[9];   // [1,2] flat
    float* out = (float*)d_out;

    // ---- mode select: fixed-cap bins (skip hist+scan) if workspace allows ----
    const size_t tail_bytes = (size_t)N_NODES * DIM * 2 * 2        // s0+s1
                            + (size_t)N_ADJ * N_NODES * 8          // rowinfo
                            + (size_t)(NBTOT + NBTOT + 1 + NBTOT + 4) * 4;
    const size_t fixed_need = (size_t)NBTOT * CAP * 8 + tail_bytes;
    const int mode = (ws_size >= fixed_need) ? 1 : 0;
    const size_t bins_elems = mode ? (size_t)NBTOT * CAP
                                   : (size_t)N_ADJ * E_EDGES;

    int2*  bins    = (int2*)d_ws;
    u16*   s0      = (u16*)(bins + bins_elems);                  // 12.8 MB bf16
    u16*   s1      = s0 + (size_t)N_NODES * DIM;                 // 12.8 MB (= s0 + NVOFF)
    int2*  rowinfo = (int2*)(s1 + (size_t)N_NODES * DIM);        // 3.2 MB
    int*   gcnt    = (int*)(rowinfo + (size_t)N_ADJ * N_NODES);  // 1564 ints
    int*   bbase   = gcnt + NBTOT;                               // 1565 ints
    int*   cursor  = bbase + NBTOT + 1;                          // 1564 ints
    int*   used    = cursor + NBTOT;                             // 4 ints

    mask_init_kernel<<<1, 1024, 0, stream>>>(idxes_seq, idxes_res, used,
                                             gcnt, bbase, cursor, mode);
    gemm_kernel<<<N_NODES / 16, 256, 0, stream>>>(x, W, b, s0);

    dim3 egrid(P1_GRIDX, N_ADJ);
    if (!mode) {
        hist_kernel<<<egrid, P1_BLK, 0, stream>>>(rows, gcnt, used);
        scan_kernel<<<1, P1_BLK, 0, stream>>>(gcnt, bbase, cursor);
    }
    place_kernel<<<egrid, P1_BLK, 0, stream>>>(rows, cols, vals, cursor, bins,
                                               used, mode ? CAP : 0);
    sort_kernel<<<NBTOT, 256, 0, stream>>>(bins, bbase, cursor, rowinfo, used);

    // s1 = 0.5*(A[i0]+A[i1]) @ s0
    gather_op_kernel<<<N_NODES / 4, 256, 0, stream>>>(s0, s1, bins, rowinfo, idxes_seq);
    // out = gelu(LN(0.5*(A[i2]+A[i3])@s1 + 0.5*(A[r0]+A[r1])@s0))
    fused_op_ln_gelu_kernel<<<N_NODES / 4, 256, 0, stream>>>(
        s0, out, bins, rowinfo, idxes_seq + 2, idxes_res, gamma, beta);
}

// Round 10
// 396.252 us; speedup vs baseline: 9.7603x; 1.0066x over previous
//
#include <hip/hip_runtime.h>
#include <hip/hip_bf16.h>
#include <math.h>

#define N_NODES 100000
#define DIM 64
#define E_EDGES 1600000
#define N_ADJ 4
#define NB 391               // ceil(100000/256) buckets of 256 rows
#define NBTOT (N_ADJ * NB)   // 1564
#define P1_BLK 1024
#define P1_CHUNK 12800
#define P1_GRIDX 125         // 125 * 12800 = 1.6M
#define CAP 5120             // fixed-cap slots/bucket: mean 4096 + 16 sigma
#define SORT_STAGE 5120      // per-bucket LDS stage (40 KB)
#define SORT_BLK 512
#define NVOFF ((u32)N_NODES * DIM)   // u16 elements between s0 and s1

typedef unsigned short u16;
typedef unsigned int u32;
typedef float f32x4 __attribute__((ext_vector_type(4)));   // native vec for nt-store

// ---- init: used-mask + gcnt zero + (fixed-cap) computed bbase/cursor ----
__global__ __launch_bounds__(1024) void mask_init_kernel(
    const int* __restrict__ iseq, const int* __restrict__ ires,
    int* __restrict__ used, int* __restrict__ gcnt,
    int* __restrict__ bbase, int* __restrict__ cursor, const int mode) {
    const int tid = threadIdx.x;
    for (int k = tid; k < NBTOT; k += 1024) {
        gcnt[k] = 0;
        if (mode) { bbase[k] = k * CAP; cursor[k] = k * CAP; }
    }
    if (tid == 0) {
        if (mode) bbase[NBTOT] = NBTOT * CAP;
        used[0] = used[1] = used[2] = used[3] = 0;
        used[iseq[0]] = 1; used[iseq[1]] = 1;
        used[iseq[2]] = 1; used[iseq[3]] = 1;
        used[ires[0]] = 1; used[ires[1]] = 1;
    }
}

// ---------------- GEMM: s0 = bf16(x @ W + b) ----------------
__global__ __launch_bounds__(256) void gemm_kernel(
    const float* __restrict__ x, const float* __restrict__ W,
    const float* __restrict__ b, u16* __restrict__ h) {
    __shared__ float Ws[DIM * DIM];
    __shared__ float xs[16 * DIM];
    const int tid = threadIdx.x;
    const long row0 = (long)blockIdx.x * 16;
    for (int i = tid; i < DIM * DIM; i += 256) Ws[i] = W[i];
    for (int i = tid; i < 16 * DIM; i += 256) xs[i] = x[row0 * DIM + i];
    __syncthreads();
    const int lane = tid & 63;
    const int grp  = tid >> 6;
    const float bias = b[lane];
    #pragma unroll
    for (int rr = 0; rr < 4; ++rr) {
        const int r = grp * 4 + rr;
        float acc = bias;
        #pragma unroll
        for (int k = 0; k < DIM; ++k)
            acc += xs[r * DIM + k] * Ws[k * DIM + lane];
        __hip_bfloat16 hb = __float2bfloat16(acc);
        h[(row0 + r) * DIM + lane] = *(u16*)&hb;
    }
}

// ---- hist (dense fallback only): bucket counts -> gcnt ----
__global__ __launch_bounds__(1024) void hist_kernel(
    const int* __restrict__ rows, int* __restrict__ gcnt,
    const int* __restrict__ used) {
    __shared__ int h[NB];
    const int a = blockIdx.y;
    if (!used[a]) return;
    const int tid = threadIdx.x;
    const long e0 = (long)a * E_EDGES + (long)blockIdx.x * P1_CHUNK;
    for (int i = tid; i < NB; i += P1_BLK) h[i] = 0;
    __syncthreads();
    for (int i = tid; i < P1_CHUNK; i += P1_BLK)
        atomicAdd(&h[rows[e0 + i] >> 8], 1);
    __syncthreads();
    for (int bk = tid; bk < NB; bk += P1_BLK) {
        const int c = h[bk];
        if (c) atomicAdd(&gcnt[a * NB + bk], c);
    }
}

// ---- scan (dense fallback only): exclusive scan of 1564 counts ----
__global__ __launch_bounds__(1024) void scan_kernel(
    const int* __restrict__ gcnt, int* __restrict__ bbase,
    int* __restrict__ cursor) {
    __shared__ int wsum[16];
    const int tid = threadIdx.x, lane = tid & 63, wave = tid >> 6;
    int pre[2];
    int tsum = 0;
    #pragma unroll
    for (int k = 0; k < 2; ++k) {
        const int idx = tid * 2 + k;
        const int v = (idx < NBTOT) ? gcnt[idx] : 0;
        pre[k] = tsum;
        tsum += v;
    }
    int incl = tsum;
    #pragma unroll
    for (int o = 1; o < 64; o <<= 1) {
        const int t = __shfl_up(incl, o);
        if (lane >= o) incl += t;
    }
    if (lane == 63) wsum[wave] = incl;
    __syncthreads();
    if (tid == 0) {
        int run = 0;
        #pragma unroll
        for (int w = 0; w < 16; ++w) { const int t = wsum[w]; wsum[w] = run; run += t; }
    }
    __syncthreads();
    const int texcl = incl - tsum + wsum[wave];
    #pragma unroll
    for (int k = 0; k < 2; ++k) {
        const int idx = tid * 2 + k;
        if (idx < NBTOT) {
            const int v = texcl + pre[k];
            bbase[idx]  = v;
            cursor[idx] = v;
        }
    }
    if (tid == 0) bbase[NBTOT] = N_ADJ * E_EDGES;
}

// ---- place: reserve per-(block,bucket) runs off preinit'd cursor, pack ----
// Record = (col<<8 | r&255, val). Row indices cached in LDS during the hist
// pass so the scatter pass never re-reads `rows` from global. cap>0 clamps
// against fixed-cap bucket overflow (probability ~0, OOB guard only).
__global__ __launch_bounds__(1024) void place_kernel(
    const int* __restrict__ rows, const int* __restrict__ cols,
    const float* __restrict__ vals, int* __restrict__ cursor,
    int2* __restrict__ bins, const int* __restrict__ used, const int cap) {
    __shared__ int h[NB];
    __shared__ int rcache[P1_CHUNK];   // 51.2 KB
    const int a = blockIdx.y;
    if (!used[a]) return;
    const int tid = threadIdx.x;
    const long e0 = (long)a * E_EDGES + (long)blockIdx.x * P1_CHUNK;
    for (int i = tid; i < NB; i += P1_BLK) h[i] = 0;
    __syncthreads();
    for (int i = tid; i < P1_CHUNK; i += P1_BLK) {
        const int r = rows[e0 + i];
        rcache[i] = r;
        atomicAdd(&h[r >> 8], 1);
    }
    __syncthreads();
    for (int bk = tid; bk < NB; bk += P1_BLK) {
        const int c = h[bk];
        if (c) h[bk] = atomicAdd(&cursor[a * NB + bk], c);  // abs base of run
    }
    __syncthreads();
    for (int i = tid; i < P1_CHUNK; i += P1_BLK) {
        const int r  = rcache[i];
        const int bk = r >> 8;
        const int slot = atomicAdd(&h[bk], 1);              // absolute bins index
        if (!cap || slot < (a * NB + bk + 1) * cap)
            bins[slot] = make_int2((cols[e0 + i] << 8) | (r & 255),
                                   __float_as_int(vals[e0 + i]));
    }
}

// ---- sort: per-bucket counting sort by r&255, emit per-row (start,count);
//      512 threads (8 serial iters over n~4096, 3 blocks/CU = 24 waves);
//      n derived from cursor-bbase; records rewritten to (col<<6, val) ----
__global__ __launch_bounds__(SORT_BLK) void sort_kernel(
    int2* __restrict__ bins, const int* __restrict__ bbase,
    const int* __restrict__ cursor, int2* __restrict__ rowinfo,
    const int* __restrict__ used) {
    __shared__ int2 stage[SORT_STAGE];
    __shared__ int h[256], off[256], cur[256], wsc[4];
    const int a   = blockIdx.x / NB;
    if (!used[a]) return;
    const int tid = threadIdx.x;
    const int bk  = blockIdx.x % NB;
    const int p0  = bbase[blockIdx.x];
    const int n   = min(cursor[blockIdx.x] - p0, SORT_STAGE);

    if (tid < 256) h[tid] = 0;
    __syncthreads();
    for (int i = tid; i < n; i += SORT_BLK) {
        const int2 e = bins[p0 + i];
        stage[i] = e;
        atomicAdd(&h[e.x & 255], 1);
    }
    __syncthreads();
    // 256-entry exclusive scan; waves 0..3 carry data, barriers full-scope
    {
        const int lane = tid & 63, wave = tid >> 6;
        const int v = (tid < 256) ? h[tid] : 0;
        int incl = v;
        #pragma unroll
        for (int o = 1; o < 64; o <<= 1) {
            const int t = __shfl_up(incl, o);
            if (lane >= o) incl += t;
        }
        if (tid < 256 && lane == 63) wsc[wave] = incl;
        __syncthreads();
        if (tid == 0) {
            int run = 0;
            #pragma unroll
            for (int w = 0; w < 4; ++w) { const int t = wsc[w]; wsc[w] = run; run += t; }
        }
        __syncthreads();
        if (tid < 256) {
            const int e = incl - v + wsc[wave];
            off[tid] = e;
            cur[tid] = e;
        }
    }
    __syncthreads();
    for (int i = tid; i < n; i += SORT_BLK) {
        const int2 e = stage[i];
        const int rank = atomicAdd(&cur[e.x & 255], 1);
        bins[p0 + rank] = make_int2(((u32)e.x >> 8) << 6, e.y);
    }
    if (tid < 256) {
        const int row = (bk << 8) + tid;
        if (row < N_NODES)
            rowinfo[a * N_NODES + row] = make_int2(p0 + off[tid], h[tid]);
    }
}

// ---------------- Pull gather core (round-2 structure, verbatim) ----------
__device__ __forceinline__ void gather4(
    const u16* __restrict__ base, const u32 nvoff,
    const int2* __restrict__ bins,
    const int2 i0, const int2 i1, const int2 i2, const int2 i3,
    const int grp, const int dsub, float acc[8])
{
    const int c1 = i0.y;
    const int c2 = c1 + i1.y;
    const int c3 = c2 + i2.y;
    const int m  = c3 + i3.y;
    const int b0 = i0.x;
    const int b1 = i1.x - c1;
    const int b2 = i2.x - c2;
    const int b3 = i3.x - c3;

    for (int T = grp; T < m; T += 32) {
        int x0, x1, x2, x3;
        float v0, v1, v2, v3;
        u32 so0, so1, so2, so3;
        #define SLOT(TT, XX, VV, SS) {                                        \
            const int t = (TT);                                               \
            int pos = b0 + t;                                                 \
            if (t >= c1) pos = b1 + t;                                        \
            if (t >= c2) pos = b2 + t;                                        \
            if (t >= c3) pos = b3 + t;                                        \
            long long raw = 0;                                                \
            if (t < m)                                                        \
                raw = __builtin_nontemporal_load((const long long*)(bins + pos)); \
            XX = (int)raw;                                                    \
            VV = __int_as_float((int)(raw >> 32));                            \
            SS = (t < c2) ? nvoff : 0u; }
        SLOT(T,      x0, v0, so0)
        SLOT(T + 8,  x1, v1, so1)
        SLOT(T + 16, x2, v2, so2)
        SLOT(T + 24, x3, v3, so3)
        #undef SLOT
        const uint4 w0 = *(const uint4*)(base + (so0 + ((u32)x0 & 0xFFFFFFC0u) + (u32)dsub));
        const uint4 w1 = *(const uint4*)(base + (so1 + ((u32)x1 & 0xFFFFFFC0u) + (u32)dsub));
        const uint4 w2 = *(const uint4*)(base + (so2 + ((u32)x2 & 0xFFFFFFC0u) + (u32)dsub));
        const uint4 w3 = *(const uint4*)(base + (so3 + ((u32)x3 & 0xFFFFFFC0u) + (u32)dsub));
        #define FMA8(W, V) {                                                  \
            acc[0] = fmaf((V), __int_as_float((W).x << 16),         acc[0]);  \
            acc[1] = fmaf((V), __int_as_float((W).x & 0xffff0000u), acc[1]);  \
            acc[2] = fmaf((V), __int_as_float((W).y << 16),         acc[2]);  \
            acc[3] = fmaf((V), __int_as_float((W).y & 0xffff0000u), acc[3]);  \
            acc[4] = fmaf((V), __int_as_float((W).z << 16),         acc[4]);  \
            acc[5] = fmaf((V), __int_as_float((W).z & 0xffff0000u), acc[5]);  \
            acc[6] = fmaf((V), __int_as_float((W).w << 16),         acc[6]);  \
            acc[7] = fmaf((V), __int_as_float((W).w & 0xffff0000u), acc[7]); }
        FMA8(w0, v0)
        FMA8(w1, v1)
        FMA8(w2, v2)
        FMA8(w3, v3)
        #undef FMA8
    }
}

__device__ __forceinline__ void reduce_groups8(float acc[8]) {
    #pragma unroll
    for (int d = 0; d < 8; ++d) {
        acc[d] += __shfl_xor(acc[d], 8);
        acc[d] += __shfl_xor(acc[d], 16);
        acc[d] += __shfl_xor(acc[d], 32);
    }
}

// s1 = bf16(0.5*(A[i0]+A[i1]) @ s0)
__global__ __launch_bounds__(256) void gather_op_kernel(
    const u16* __restrict__ s0, u16* __restrict__ dst,
    const int2* __restrict__ bins, const int2* __restrict__ rowinfo,
    const int* __restrict__ idx) {
    const int lane = threadIdx.x & 63;
    const int row  = blockIdx.x * 4 + (threadIdx.x >> 6);
    const int grp  = lane >> 3;
    const int sub  = lane & 7;
    const int dsub = sub << 3;
    const int2 i0 = rowinfo[idx[0] * N_NODES + row];
    const int2 i1 = rowinfo[idx[1] * N_NODES + row];
    const int2 iz = make_int2(0, 0);
    float acc[8] = {0.f, 0.f, 0.f, 0.f, 0.f, 0.f, 0.f, 0.f};
    gather4(s0, 0u, bins, i0, i1, iz, iz, grp, dsub, acc);
    reduce_groups8(acc);
    if (grp == 0) {
        u32 p[4];
        #pragma unroll
        for (int q = 0; q < 4; ++q) {
            __hip_bfloat16 blo = __float2bfloat16(0.5f * acc[2 * q]);
            __hip_bfloat16 bhi = __float2bfloat16(0.5f * acc[2 * q + 1]);
            p[q] = (u32)(*(u16*)&blo) | ((u32)(*(u16*)&bhi) << 16);
        }
        *(uint4*)(dst + (long)row * DIM + dsub) = make_uint4(p[0], p[1], p[2], p[3]);
    }
}

// out = gelu(LN(0.5*(seq@s1) + 0.5*(res@s0)))
__global__ __launch_bounds__(256) void fused_op_ln_gelu_kernel(
    const u16* __restrict__ s0, float* __restrict__ out,
    const int2* __restrict__ bins, const int2* __restrict__ rowinfo,
    const int* __restrict__ idx_seq1, const int* __restrict__ idx_res,
    const float* __restrict__ gamma, const float* __restrict__ beta) {
    const int lane = threadIdx.x & 63;
    const int row  = blockIdx.x * 4 + (threadIdx.x >> 6);
    const int grp  = lane >> 3;
    const int sub  = lane & 7;
    const int dsub = sub << 3;
    // segments 0,1 gather from s1 (= s0 + NVOFF via nvoff), 2,3 from s0
    const int2 i0 = rowinfo[idx_seq1[0] * N_NODES + row];
    const int2 i1 = rowinfo[idx_seq1[1] * N_NODES + row];
    const int2 i2 = rowinfo[idx_res[0]  * N_NODES + row];
    const int2 i3 = rowinfo[idx_res[1]  * N_NODES + row];
    float acc[8] = {0.f, 0.f, 0.f, 0.f, 0.f, 0.f, 0.f, 0.f};
    gather4(s0, NVOFF, bins, i0, i1, i2, i3, grp, dsub, acc);
    reduce_groups8(acc);
    #pragma unroll
    for (int d = 0; d < 8; ++d) acc[d] *= 0.5f;
    float s = 0.f, s2 = 0.f;
    #pragma unroll
    for (int d = 0; d < 8; ++d) { s += acc[d]; s2 += acc[d] * acc[d]; }
    s  += __shfl_xor(s, 1);  s  += __shfl_xor(s, 2);  s  += __shfl_xor(s, 4);
    s2 += __shfl_xor(s2, 1); s2 += __shfl_xor(s2, 2); s2 += __shfl_xor(s2, 4);
    const float mu  = s * (1.0f / DIM);
    const float var = s2 * (1.0f / DIM) - mu * mu;
    const float inv = rsqrtf(var + 1e-5f);
    if (grp == 0) {
        const float4 gm0 = ((const float4*)gamma)[sub * 2];
        const float4 gm1 = ((const float4*)gamma)[sub * 2 + 1];
        const float4 bt0 = ((const float4*)beta)[sub * 2];
        const float4 bt1 = ((const float4*)beta)[sub * 2 + 1];
        float y[8];
        y[0] = (acc[0] - mu) * inv * gm0.x + bt0.x;
        y[1] = (acc[1] - mu) * inv * gm0.y + bt0.y;
        y[2] = (acc[2] - mu) * inv * gm0.z + bt0.z;
        y[3] = (acc[3] - mu) * inv * gm0.w + bt0.w;
        y[4] = (acc[4] - mu) * inv * gm1.x + bt1.x;
        y[5] = (acc[5] - mu) * inv * gm1.y + bt1.y;
        y[6] = (acc[6] - mu) * inv * gm1.z + bt1.z;
        y[7] = (acc[7] - mu) * inv * gm1.w + bt1.w;
        f32x4 o0, o1;
        o0.x = 0.5f * y[0] * (1.0f + erff(y[0] * 0.70710678118654752f));
        o0.y = 0.5f * y[1] * (1.0f + erff(y[1] * 0.70710678118654752f));
        o0.z = 0.5f * y[2] * (1.0f + erff(y[2] * 0.70710678118654752f));
        o0.w = 0.5f * y[3] * (1.0f + erff(y[3] * 0.70710678118654752f));
        o1.x = 0.5f * y[4] * (1.0f + erff(y[4] * 0.70710678118654752f));
        o1.y = 0.5f * y[5] * (1.0f + erff(y[5] * 0.70710678118654752f));
        o1.z = 0.5f * y[6] * (1.0f + erff(y[6] * 0.70710678118654752f));
        o1.w = 0.5f * y[7] * (1.0f + erff(y[7] * 0.70710678118654752f));
        // final output: never re-read -> nontemporal, keep L2 for gather tables
        f32x4* po = (f32x4*)(out + (long)row * DIM + dsub);
        __builtin_nontemporal_store(o0, po);
        __builtin_nontemporal_store(o1, po + 1);
    }
}

extern "C" void kernel_launch(void* const* d_in, const int* in_sizes, int n_in,
                              void* d_out, int out_size, void* d_ws, size_t ws_size,
                              hipStream_t stream) {
    const float* x     = (const float*)d_in[0];
    const float* W     = (const float*)d_in[1];
    const float* b     = (const float*)d_in[2];
    const int*   rows  = (const int*)d_in[3];
    const int*   cols  = (const int*)d_in[4];
    const float* vals  = (const float*)d_in[5];
    const float* gamma = (const float*)d_in[6];
    const float* beta  = (const float*)d_in[7];
    const int*   idxes_seq = (const int*)d_in[8];   // [2,2] flat
    const int*   idxes_res = (const int*)d_in[9];   // [1,2] flat
    float* out = (float*)d_out;

    // ---- mode select: fixed-cap bins (skip hist+scan) if workspace allows ----
    const size_t tail_bytes = (size_t)N_NODES * DIM * 2 * 2        // s0+s1
                            + (size_t)N_ADJ * N_NODES * 8          // rowinfo
                            + (size_t)(NBTOT + NBTOT + 1 + NBTOT + 4) * 4;
    const size_t fixed_need = (size_t)NBTOT * CAP * 8 + tail_bytes;
    const int mode = (ws_size >= fixed_need) ? 1 : 0;
    const size_t bins_elems = mode ? (size_t)NBTOT * CAP
                                   : (size_t)N_ADJ * E_EDGES;

    int2*  bins    = (int2*)d_ws;
    u16*   s0      = (u16*)(bins + bins_elems);                  // 12.8 MB bf16
    u16*   s1      = s0 + (size_t)N_NODES * DIM;                 // 12.8 MB (= s0 + NVOFF)
    int2*  rowinfo = (int2*)(s1 + (size_t)N_NODES * DIM);        // 3.2 MB
    int*   gcnt    = (int*)(rowinfo + (size_t)N_ADJ * N_NODES);  // 1564 ints
    int*   bbase   = gcnt + NBTOT;                               // 1565 ints
    int*   cursor  = bbase + NBTOT + 1;                          // 1564 ints
    int*   used    = cursor + NBTOT;                             // 4 ints

    mask_init_kernel<<<1, 1024, 0, stream>>>(idxes_seq, idxes_res, used,
                                             gcnt, bbase, cursor, mode);
    gemm_kernel<<<N_NODES / 16, 256, 0, stream>>>(x, W, b, s0);

    dim3 egrid(P1_GRIDX, N_ADJ);
    if (!mode) {
        hist_kernel<<<egrid, P1_BLK, 0, stream>>>(rows, gcnt, used);
        scan_kernel<<<1, P1_BLK, 0, stream>>>(gcnt, bbase, cursor);
    }
    place_kernel<<<egrid, P1_BLK, 0, stream>>>(rows, cols, vals, cursor, bins,
                                               used, mode ? CAP : 0);
    sort_kernel<<<NBTOT, SORT_BLK, 0, stream>>>(bins, bbase, cursor, rowinfo, used);

    // s1 = 0.5*(A[i0]+A[i1]) @ s0
    gather_op_kernel<<<N_NODES / 4, 256, 0, stream>>>(s0, s1, bins, rowinfo, idxes_seq);
    // out = gelu(LN(0.5*(A[i2]+A[i3])@s1 + 0.5*(A[r0]+A[r1])@s0))
    fused_op_ln_gelu_kernel<<<N_NODES / 4, 256, 0, stream>>>(
        s0, out, bins, rowinfo, idxes_seq + 2, idxes_res, gamma, beta);
}